// Round 3
// baseline (437.555 us; speedup 1.0000x reference)
//
#include <hip/hip_runtime.h>
#include <cmath>

#define HIDDEN 2048
#define NH 16
#define NKV 4
#define HD 128
#define SEQ 2048
#define BATCH 2

typedef unsigned short ushort_t;
typedef short bf16x8 __attribute__((ext_vector_type(8)));
typedef float f32x4 __attribute__((ext_vector_type(4)));
typedef ushort_t u16x4 __attribute__((ext_vector_type(4)));

__device__ __forceinline__ ushort_t f2bf(float f) {
    union { float f; unsigned int u; } v; v.f = f;
    unsigned int r = v.u + 0x7fffu + ((v.u >> 16) & 1u);
    return (ushort_t)(r >> 16);
}
__device__ __forceinline__ ushort_t f2bf_trunc(float f) {
    union { float f; unsigned int u; } v; v.f = f;
    return (ushort_t)(v.u >> 16);
}

__device__ __forceinline__ f32x4 mfma16(bf16x8 a, bf16x8 b, f32x4 c) {
    return __builtin_amdgcn_mfma_f32_16x16x32_bf16(a, b, c, 0, 0, 0);
}

// async global -> LDS, 16B per lane. LDS dst is wave-uniform base + lane*16.
__device__ __forceinline__ void load_lds16(const void* g, void* l) {
    __builtin_amdgcn_global_load_lds((const __attribute__((address_space(1))) unsigned int*)g,
                                     (__attribute__((address_space(3))) unsigned int*)l,
                                     16, 0, 0);
}

// Bank-swizzle scheme for [rows x 32shorts] tiles staged via global_load_lds:
// 16B-chunk c of row p lives at chunk-position cp = c ^ ((p>>1)&3).
// Staging lane l (p=l>>2, cp=l&3) loads global chunk (l&3)^((l>>3)&3).
// Reader of chunk q at row r uses position q^((r>>1)&3). -> conflict-free (measured 0).

// ---------------- elementwise fp32 -> bf16 ----------------
__global__ __launch_bounds__(256) void convert_x(const float* __restrict__ x,
                                                 ushort_t* __restrict__ xb, int n4) {
    int g = blockIdx.x * 256 + threadIdx.x;
    if (g >= n4) return;
    float4 v = ((const float4*)x)[g];
    u16x4 o;
    o[0] = f2bf(v.x); o[1] = f2bf(v.y); o[2] = f2bf(v.z); o[3] = f2bf(v.w);
    ((u16x4*)xb)[g] = o;
}

// ---------------- all weights: W [K][N] fp32 -> WT [N][K] bf16, one launch ----------------
__global__ __launch_bounds__(256) void transpose_all(const float* __restrict__ Wq,
                                                     const float* __restrict__ Wk,
                                                     const float* __restrict__ Wv,
                                                     const float* __restrict__ Wo,
                                                     ushort_t* __restrict__ WqkvT,
                                                     ushort_t* __restrict__ WoT) {
    const int z = blockIdx.z;
    const float* W;
    ushort_t* WT;
    int N;
    if (z == 0)      { W = Wq; WT = WqkvT;                        N = 2048; }
    else if (z == 1) { W = Wk; WT = WqkvT + 2048ull * 2048;       N = 512;  }
    else if (z == 2) { W = Wv; WT = WqkvT + 2560ull * 2048;       N = 512;  }
    else             { W = Wo; WT = WoT;                          N = 2048; }
    const int K = 2048;
    const int n0 = blockIdx.x * 64, k0 = blockIdx.y * 64;
    if (n0 >= N) return;
    __shared__ ushort_t T[64][72];
    const int t = threadIdx.x;
    for (int idx = t; idx < 64 * 16; idx += 256) {
        int r = idx >> 4, c4 = (idx & 15) << 2;
        float4 v = *(const float4*)&W[(size_t)(k0 + r) * N + n0 + c4];
        T[r][c4 + 0] = f2bf(v.x); T[r][c4 + 1] = f2bf(v.y);
        T[r][c4 + 2] = f2bf(v.z); T[r][c4 + 3] = f2bf(v.w);
    }
    __syncthreads();
    for (int idx = t; idx < 64 * 16; idx += 256) {
        int n = idx >> 4, kg = (idx & 15) << 2;
        u16x4 o;
        o[0] = T[kg + 0][n]; o[1] = T[kg + 1][n];
        o[2] = T[kg + 2][n]; o[3] = T[kg + 3][n];
        *(u16x4*)&WT[(size_t)(n0 + n) * K + k0 + kg] = o;
    }
}

// ---------------- 128x128-tile GEMM, ring-3 counted-vmcnt pipeline ----------------
// C = A[M][K] * Bt[N][K]^T + bias, fused epilogues.
// 256 threads = 4 waves (2x2); per-wave output 64x64 (acc[4][4], 8 ds_read : 16 MFMA).
// BK=32, 3-deep LDS ring (48 KiB total) -> 3 blocks/CU. Prefetch 2 K-tiles ahead.
// Main loop: stage(t+2); s_waitcnt vmcnt(8); s_barrier; compute (setprio-wrapped);
// s_barrier. vmcnt never drains to 0 until the tail.
// Column tiles per wave INTERLEAVED: wave wc owns tiles {wc, wc+2, wc+4, wc+6},
// so RoPE pair (dl, dl+64) = (acc[i][p], acc[i][p+2]) stays in-wave.
// MODE 0: fp32 out + bias (final proj).
// MODE 2: fused QKV (N=3072): n0<2048 -> RoPE+scale Qr; [2048,2560) -> RoPE Kr;
//         n0>=2560 -> Vt transposed store.
template <int MODE>
__global__ __launch_bounds__(256) void gemm128(const ushort_t* __restrict__ A,
                                               const ushort_t* __restrict__ Bt,
                                               const float* __restrict__ bias,
                                               const float* __restrict__ bias2,
                                               const float* __restrict__ bias3,
                                               void* __restrict__ out,
                                               void* __restrict__ out2,
                                               void* __restrict__ out3,
                                               int M, int N, int K,
                                               const int* __restrict__ posids) {
    __shared__ __align__(16) ushort_t Asb[3 * 4096];  // 3 bufs x (128 rows x 32 shorts)
    __shared__ __align__(16) ushort_t Bsb[3 * 4096];
    const int tid = threadIdx.x;
    const int w = tid >> 6, lane = tid & 63, quad = lane >> 4, l16 = lane & 15;
    const int wr = w >> 1, wc = w & 1;  // 2x2 wave grid
    const int m0 = blockIdx.y * 128, n0 = blockIdx.x * 128;

    f32x4 acc[4][4];
#pragma unroll
    for (int i = 0; i < 4; i++)
#pragma unroll
        for (int j = 0; j < 4; j++)
#pragma unroll
            for (int e = 0; e < 4; e++) acc[i][j][e] = 0.0f;

    // staging: lane -> row-of-16 + swizzled 16B chunk; 4 insts/thread per K-tile
    const int rr = lane >> 2;
    const int gc8 = (((lane & 3) ^ ((lane >> 3) & 3)) << 3);
    const ushort_t* Ag = A + (size_t)(m0 + w * 32 + rr) * K + gc8;
    const ushort_t* Bg = Bt + (size_t)(n0 + w * 32 + rr) * K + gc8;
    ushort_t* Asw = Asb + w * 1024;  // wave's 32-row slice
    ushort_t* Bsw = Bsb + w * 1024;

    auto stage = [&](int t, int buf) {
        const int k0 = t * 32;
        const ushort_t* ag = Ag + k0;
        const ushort_t* bg = Bg + k0;
        ushort_t* la = Asw + buf * 4096;
        ushort_t* lb = Bsw + buf * 4096;
        load_lds16(ag, la);
        load_lds16(ag + (size_t)16 * K, la + 512);
        load_lds16(bg, lb);
        load_lds16(bg + (size_t)16 * K, lb + 512);
    };

    const int rsw = (l16 >> 1) & 3;  // reader swizzle
    const int aoff = (wr * 64 + l16) * 32 + ((quad ^ rsw) << 3);
    const int boff = (wc * 16 + l16) * 32 + ((quad ^ rsw) << 3);

    auto compute = [&](int buf) {
        const ushort_t* Ab = Asb + buf * 4096 + aoff;
        const ushort_t* Bb = Bsb + buf * 4096 + boff;
        bf16x8 af[4], bfr[4];
#pragma unroll
        for (int i = 0; i < 4; i++) af[i] = *(const bf16x8*)&Ab[i * 512];
#pragma unroll
        for (int j = 0; j < 4; j++) bfr[j] = *(const bf16x8*)&Bb[j * 1024];  // tile wc+2j
        __builtin_amdgcn_s_setprio(1);
#pragma unroll
        for (int i = 0; i < 4; i++)
#pragma unroll
            for (int j = 0; j < 4; j++) acc[i][j] = mfma16(af[i], bfr[j], acc[i][j]);
        __builtin_amdgcn_s_setprio(0);
    };

    const int nt = K >> 5;  // 64 K-tiles
    stage(0, 0);
    stage(1, 1);
    int cur = 0, nx = 2;
    for (int t = 0; t < nt - 2; ++t) {
        stage(t + 2, nx);
        asm volatile("s_waitcnt vmcnt(8)" ::: "memory");  // tile t landed; t+1,t+2 in flight
        __builtin_amdgcn_s_barrier();
        __builtin_amdgcn_sched_barrier(0);
        compute(cur);
        __builtin_amdgcn_sched_barrier(0);
        __builtin_amdgcn_s_barrier();
        cur = (cur == 2) ? 0 : cur + 1;
        nx = (nx == 2) ? 0 : nx + 1;
    }
    asm volatile("s_waitcnt vmcnt(4)" ::: "memory");
    __builtin_amdgcn_s_barrier();
    __builtin_amdgcn_sched_barrier(0);
    compute(cur);
    __builtin_amdgcn_sched_barrier(0);
    __builtin_amdgcn_s_barrier();
    cur = (cur == 2) ? 0 : cur + 1;
    asm volatile("s_waitcnt vmcnt(0)" ::: "memory");
    __builtin_amdgcn_s_barrier();
    __builtin_amdgcn_sched_barrier(0);
    compute(cur);

    // ---- epilogues (round-1 verified decomposition) ----
    if (MODE == 0) {
        float* O = (float*)out;
#pragma unroll
        for (int i = 0; i < 4; i++)
#pragma unroll
            for (int r = 0; r < 4; r++) {
                int row = m0 + wr * 64 + i * 16 + quad * 4 + r;
#pragma unroll
                for (int j = 0; j < 4; j++) {
                    int col = n0 + (wc + 2 * j) * 16 + l16;
                    O[(size_t)row * N + col] = acc[i][j][r] + bias[col];
                }
            }
    } else {  // MODE 2: fused QKV
        if (n0 < 2048) {  // Q path: RoPE + scale
            ushort_t* O = (ushort_t*)out;
            const int h = n0 >> 7;
            const float scale = 0.08838834764831845f;
            float fr[2];
#pragma unroll
            for (int p = 0; p < 2; p++)
                fr[p] = __expf(-0.21586735246819178f * (float)((wc + 2 * p) * 16 + l16));
#pragma unroll
            for (int i = 0; i < 4; i++)
#pragma unroll
                for (int r = 0; r < 4; r++) {
                    int row = m0 + wr * 64 + i * 16 + quad * 4 + r;  // b*SEQ + s
                    int b = row >> 11, s = row & (SEQ - 1);
                    float pos = (float)posids[row];
                    size_t obase = ((size_t)(b * NH + h) * SEQ + s) * HD;
#pragma unroll
                    for (int p = 0; p < 2; p++) {
                        int dl = (wc + 2 * p) * 16 + l16;  // 0..63
                        float x1 = acc[i][p][r] + bias[n0 + dl];
                        float x2 = acc[i][p + 2][r] + bias[n0 + dl + 64];
                        float sn, cs;
                        __sincosf(pos * fr[p], &sn, &cs);
                        O[obase + dl]      = f2bf((x1 * cs - x2 * sn) * scale);
                        O[obase + dl + 64] = f2bf((x2 * cs + x1 * sn) * scale);
                    }
                }
        } else if (n0 < 2560) {  // K path: RoPE
            ushort_t* O = (ushort_t*)out2;
            const int n0k = n0 - 2048;
            const int h = n0k >> 7;
            float fr[2];
#pragma unroll
            for (int p = 0; p < 2; p++)
                fr[p] = __expf(-0.21586735246819178f * (float)((wc + 2 * p) * 16 + l16));
#pragma unroll
            for (int i = 0; i < 4; i++)
#pragma unroll
                for (int r = 0; r < 4; r++) {
                    int row = m0 + wr * 64 + i * 16 + quad * 4 + r;
                    int b = row >> 11, s = row & (SEQ - 1);
                    float pos = (float)posids[row];
                    size_t obase = ((size_t)(b * NKV + h) * SEQ + s) * HD;
#pragma unroll
                    for (int p = 0; p < 2; p++) {
                        int dl = (wc + 2 * p) * 16 + l16;
                        float x1 = acc[i][p][r] + bias2[n0k + dl];
                        float x2 = acc[i][p + 2][r] + bias2[n0k + dl + 64];
                        float sn, cs;
                        __sincosf(pos * fr[p], &sn, &cs);
                        O[obase + dl]      = f2bf(x1 * cs - x2 * sn);
                        O[obase + dl + 64] = f2bf(x2 * cs + x1 * sn);
                    }
                }
        } else {  // V path: transposed store
            ushort_t* O = (ushort_t*)out3;
            const int n0v = n0 - 2560;
            const int h = n0v >> 7;
#pragma unroll
            for (int i = 0; i < 4; i++)
#pragma unroll
                for (int r = 0; r < 4; r++) {
                    int row = m0 + wr * 64 + i * 16 + quad * 4 + r;
                    int b = row >> 11, s = row & (SEQ - 1);
#pragma unroll
                    for (int j = 0; j < 4; j++) {
                        int d = (wc + 2 * j) * 16 + l16;  // head dim 0..127
                        float v = acc[i][j][r] + bias3[n0v + d];
                        O[((size_t)(b * NKV + h) * HD + d) * SEQ + s] = f2bf(v);
                    }
                }
        }
    }
}

// ---------------- causal GQA flash attention ----------------
// K staged in LDS (dbuf); V read DIRECTLY from global (L2-resident, m169 lesson).
// LDS 41 KiB -> 3 blocks/CU (was 73 KiB / 2 blocks).
__global__ __launch_bounds__(256) void flash(const ushort_t* __restrict__ Qr,
                                             const ushort_t* __restrict__ Kr,
                                             const ushort_t* __restrict__ Vt,
                                             ushort_t* __restrict__ Attn) {
    __shared__ __align__(16) ushort_t Ksh[2 * 4 * 64 * 32];   // 32 KB
    __shared__ __align__(16) ushort_t Ps[4 * 16 * 72];        // 9 KB, per-wave
    const int tid = threadIdx.x;
    const int w = tid >> 6, lane = tid & 63, quad = lane >> 4, l16 = lane & 15;
    const int x = blockIdx.x, h = blockIdx.y, b = blockIdx.z;
    const int qt = b ? x : (gridDim.x - 1 - x);
    const int q0 = qt * 128;
    const int nkt = 2 * qt + 2;
    const int hkv = h >> 2;
    const ushort_t* Kg = Kr + ((size_t)(b * NKV + hkv) * SEQ) * HD;
    const ushort_t* Vg = Vt + ((size_t)(b * NKV + hkv) * HD) * SEQ;

    const int p = lane >> 2;
    const int gc8 = (((lane & 3) ^ ((lane >> 3) & 3)) << 3);
    const ushort_t* kst = Kg + (size_t)p * HD + w * 32 + gc8;
    ushort_t* ksl = Ksh + w * 2048;

    auto stage = [&](int bi, int kv0) {
        const ushort_t* gk = kst + (size_t)kv0 * HD;
        ushort_t* lk = ksl + bi * 8192;
        load_lds16(gk, lk);
        load_lds16(gk + (size_t)16 * HD, lk + 512);
        load_lds16(gk + (size_t)32 * HD, lk + 1024);
        load_lds16(gk + (size_t)48 * HD, lk + 1536);
    };

    bf16x8 aq[2][4];
#pragma unroll
    for (int st = 0; st < 2; st++) {
        const size_t qrow = ((size_t)(b * NH + h) * SEQ + q0 + st * 64 + w * 16 + l16) * HD;
#pragma unroll
        for (int kc = 0; kc < 4; kc++)
            aq[st][kc] = *(const bf16x8*)&Qr[qrow + kc * 32 + quad * 8];
    }

    f32x4 o[2][8];
#pragma unroll
    for (int st = 0; st < 2; st++)
#pragma unroll
        for (int j = 0; j < 8; j++)
#pragma unroll
            for (int e = 0; e < 4; e++) o[st][j][e] = 0.0f;
    f32x4 ls2[2];
#pragma unroll
    for (int st = 0; st < 2; st++)
        for (int e = 0; e < 4; e++) ls2[st][e] = 0.0f;
    bf16x8 ones;
#pragma unroll
    for (int e = 0; e < 8; e++) ones[e] = (short)0x3F80;  // bf16 1.0

    ushort_t* Pw = &Ps[w * 16 * 72];
    const int rsw8 = ((l16 >> 1) & 3) << 3;

    stage(0, 0);
    __syncthreads();

    for (int kt = 0; kt < nkt; kt++) {
        const int kv0 = kt * 64;
        const int cur = kt & 1;
        if (kt + 1 < nkt) stage(cur ^ 1, kv0 + 64);

        const ushort_t* Kb = Ksh + cur * 8192;

#pragma unroll
        for (int st = 0; st < 2; st++) {
            if (st == 0 && kt == 2 * qt + 1) continue;

            f32x4 sa[4];
#pragma unroll
            for (int nt = 0; nt < 4; nt++)
#pragma unroll
                for (int e = 0; e < 4; e++) sa[nt][e] = 0.0f;
#pragma unroll
            for (int kc = 0; kc < 4; kc++) {
#pragma unroll
                for (int nt = 0; nt < 4; nt++) {
                    bf16x8 bk = *(const bf16x8*)&Kb[kc * 2048 + nt * 512 + l16 * 32 +
                                                    ((quad * 8) ^ rsw8)];
                    sa[nt] = mfma16(aq[st][kc], bk, sa[nt]);
                }
            }

            if ((kt >> 1) == qt && (kt & 1) == st) {
#pragma unroll
                for (int nt = 0; nt < 4; nt++)
#pragma unroll
                    for (int r = 0; r < 4; r++) {
                        int kvg = kv0 + nt * 16 + l16;
                        int qg = q0 + st * 64 + w * 16 + quad * 4 + r;
                        if (kvg > qg) sa[nt][r] = -1e30f;
                    }
            }

#pragma unroll
            for (int nt = 0; nt < 4; nt++)
#pragma unroll
                for (int r = 0; r < 4; r++)
                    Pw[(quad * 4 + r) * 72 + nt * 16 + l16] = f2bf_trunc(__expf(sa[nt][r]));

            // PV: V fragments straight from global (L2-resident)
#pragma unroll
            for (int kc = 0; kc < 2; kc++) {
                bf16x8 ap = *(const bf16x8*)&Pw[l16 * 72 + kc * 32 + quad * 8];
                ls2[st] = mfma16(ap, ones, ls2[st]);
#pragma unroll
                for (int j = 0; j < 8; j++) {
                    bf16x8 bv = *(const bf16x8*)&Vg[(size_t)(j * 16 + l16) * SEQ +
                                                    kv0 + kc * 32 + quad * 8];
                    o[st][j] = mfma16(ap, bv, o[st][j]);
                }
            }
        }
        __syncthreads();
    }

#pragma unroll
    for (int st = 0; st < 2; st++)
#pragma unroll
        for (int r = 0; r < 4; r++) {
            float inv = 1.0f / ls2[st][r];
            int row = b * SEQ + q0 + st * 64 + w * 16 + quad * 4 + r;
            size_t obase = (size_t)row * HIDDEN + h * HD;
#pragma unroll
            for (int j = 0; j < 8; j++) Attn[obase + j * 16 + l16] = f2bf(o[st][j][r] * inv);
        }
}

extern "C" void kernel_launch(void* const* d_in, const int* in_sizes, int n_in,
                              void* d_out, int out_size, void* d_ws, size_t ws_size,
                              hipStream_t stream) {
    const float* hs = (const float*)d_in[0];
    const int* posids = (const int*)d_in[1];
    const float* Wq = (const float*)d_in[2];
    const float* bq = (const float*)d_in[3];
    const float* Wk = (const float*)d_in[4];
    const float* bk = (const float*)d_in[5];
    const float* Wv = (const float*)d_in[6];
    const float* bv = (const float*)d_in[7];
    const float* Wo = (const float*)d_in[8];
    const float* bo = (const float*)d_in[9];
    float* out = (float*)d_out;

    char* ws = (char*)d_ws;
    size_t off = 0;
    auto alloc = [&](size_t bytes) {
        char* p = ws + off;
        off += (bytes + 255) & ~(size_t)255;
        return p;
    };
    ushort_t* Xb     = (ushort_t*)alloc(4096ull * 2048 * 2);
    ushort_t* WqkvT  = (ushort_t*)alloc(3072ull * 2048 * 2);
    ushort_t* WoT    = (ushort_t*)alloc(2048ull * 2048 * 2);
    ushort_t* Qr     = (ushort_t*)alloc((size_t)BATCH * NH * SEQ * HD * 2);
    ushort_t* Kr     = (ushort_t*)alloc((size_t)BATCH * NKV * SEQ * HD * 2);
    ushort_t* Vtr    = (ushort_t*)alloc((size_t)BATCH * NKV * HD * SEQ * 2);
    ushort_t* Attn   = (ushort_t*)alloc(4096ull * 2048 * 2);

    convert_x<<<4096 * 2048 / 4 / 256, 256, 0, stream>>>(hs, Xb, 4096 * 2048 / 4);
    transpose_all<<<dim3(32, 32, 4), 256, 0, stream>>>(Wq, Wk, Wv, Wo, WqkvT, WoT);

    gemm128<2><<<dim3(24, 32), 256, 0, stream>>>(Xb, WqkvT, bq, bk, bv,
                                                 Qr, Kr, Vtr, 4096, 3072, 2048, posids);

    flash<<<dim3(SEQ / 128, NH, BATCH), 256, 0, stream>>>(Qr, Kr, Vtr, Attn);

    gemm128<0><<<dim3(16, 32), 256, 0, stream>>>(Attn, WoT, bo, nullptr, nullptr,
                                                 out, nullptr, nullptr, 4096, 2048, 2048, nullptr);
}

// Round 4
// 365.955 us; speedup vs baseline: 1.1957x; 1.1957x over previous
//
#include <hip/hip_runtime.h>
#include <cmath>

#define HIDDEN 2048
#define NH 16
#define NKV 4
#define HD 128
#define SEQ 2048
#define BATCH 2

typedef unsigned short ushort_t;
typedef short bf16x8 __attribute__((ext_vector_type(8)));
typedef float f32x4 __attribute__((ext_vector_type(4)));
typedef ushort_t u16x4 __attribute__((ext_vector_type(4)));

__device__ __forceinline__ ushort_t f2bf(float f) {
    union { float f; unsigned int u; } v; v.f = f;
    unsigned int r = v.u + 0x7fffu + ((v.u >> 16) & 1u);
    return (ushort_t)(r >> 16);
}
__device__ __forceinline__ ushort_t f2bf_trunc(float f) {
    union { float f; unsigned int u; } v; v.f = f;
    return (ushort_t)(v.u >> 16);
}

__device__ __forceinline__ f32x4 mfma16(bf16x8 a, bf16x8 b, f32x4 c) {
    return __builtin_amdgcn_mfma_f32_16x16x32_bf16(a, b, c, 0, 0, 0);
}

// async global -> LDS, 16B per lane. LDS dst is wave-uniform base + lane*16.
__device__ __forceinline__ void load_lds16(const void* g, void* l) {
    __builtin_amdgcn_global_load_lds((const __attribute__((address_space(1))) unsigned int*)g,
                                     (__attribute__((address_space(3))) unsigned int*)l,
                                     16, 0, 0);
}

// Bank-swizzle scheme for [rows x 32shorts] tiles staged via global_load_lds:
// 16B-chunk c of row p lives at chunk-position cp = c ^ ((p>>1)&3).
// Staging lane l (p=l>>2, cp=l&3) loads global chunk (l&3)^((l>>3)&3).
// Reader of chunk q at row r uses position q^((r>>1)&3). -> conflict-free (measured 0).

// ---------------- elementwise fp32 -> bf16 ----------------
__global__ __launch_bounds__(256) void convert_x(const float* __restrict__ x,
                                                 ushort_t* __restrict__ xb, int n4) {
    int g = blockIdx.x * 256 + threadIdx.x;
    if (g >= n4) return;
    float4 v = ((const float4*)x)[g];
    u16x4 o;
    o[0] = f2bf(v.x); o[1] = f2bf(v.y); o[2] = f2bf(v.z); o[3] = f2bf(v.w);
    ((u16x4*)xb)[g] = o;
}

// ---------------- all weights: W [K][N] fp32 -> WT [N][K] bf16, one launch ----------------
__global__ __launch_bounds__(256) void transpose_all(const float* __restrict__ Wq,
                                                     const float* __restrict__ Wk,
                                                     const float* __restrict__ Wv,
                                                     const float* __restrict__ Wo,
                                                     ushort_t* __restrict__ WqkvT,
                                                     ushort_t* __restrict__ WoT) {
    const int z = blockIdx.z;
    const float* W;
    ushort_t* WT;
    int N;
    if (z == 0)      { W = Wq; WT = WqkvT;                        N = 2048; }
    else if (z == 1) { W = Wk; WT = WqkvT + 2048ull * 2048;       N = 512;  }
    else if (z == 2) { W = Wv; WT = WqkvT + 2560ull * 2048;       N = 512;  }
    else             { W = Wo; WT = WoT;                          N = 2048; }
    const int K = 2048;
    const int n0 = blockIdx.x * 64, k0 = blockIdx.y * 64;
    if (n0 >= N) return;
    __shared__ ushort_t T[64][72];
    const int t = threadIdx.x;
    for (int idx = t; idx < 64 * 16; idx += 256) {
        int r = idx >> 4, c4 = (idx & 15) << 2;
        float4 v = *(const float4*)&W[(size_t)(k0 + r) * N + n0 + c4];
        T[r][c4 + 0] = f2bf(v.x); T[r][c4 + 1] = f2bf(v.y);
        T[r][c4 + 2] = f2bf(v.z); T[r][c4 + 3] = f2bf(v.w);
    }
    __syncthreads();
    for (int idx = t; idx < 64 * 16; idx += 256) {
        int n = idx >> 4, kg = (idx & 15) << 2;
        u16x4 o;
        o[0] = T[kg + 0][n]; o[1] = T[kg + 1][n];
        o[2] = T[kg + 2][n]; o[3] = T[kg + 3][n];
        *(u16x4*)&WT[(size_t)(n0 + n) * K + k0 + kg] = o;
    }
}

// ---------------- 256x256-tile GEMM, counted-vmcnt pipeline (verified r2) ----------------
// C = A[M][K] * Bt[N][K]^T + bias, fused epilogues.
// 512 threads = 8 waves (2 row x 4 col); per-wave output 128x64 (acc[8][4]).
// BK=32, 3-deep LDS ring (96 KiB), prefetch 2 K-tiles ahead.
// Main loop: stage(t+2); s_waitcnt vmcnt(8); s_barrier; 12 ds_read + 32 MFMA
// (setprio-wrapped); s_barrier.  vmcnt never drains to 0 until the tail.
// Column tiles per wave INTERLEAVED: wave wc owns tiles {wc, wc+4, wc+8, wc+12},
// so RoPE pair (dl, dl+64) = frags (2p, 2p+1) stays in-wave.
template <int MODE>
__global__ __launch_bounds__(512) void gemm256(const ushort_t* __restrict__ A,
                                               const ushort_t* __restrict__ Bt,
                                               const float* __restrict__ bias,
                                               const float* __restrict__ bias2,
                                               const float* __restrict__ bias3,
                                               void* __restrict__ out,
                                               void* __restrict__ out2,
                                               void* __restrict__ out3,
                                               int M, int N, int K,
                                               const int* __restrict__ posids) {
    __shared__ __align__(16) ushort_t Asb[3 * 8192];  // 3 bufs x (256 rows x 32 shorts)
    __shared__ __align__(16) ushort_t Bsb[3 * 8192];
    const int tid = threadIdx.x;
    const int w = tid >> 6, lane = tid & 63, quad = lane >> 4, l16 = lane & 15;
    const int wr = w >> 2, wc = w & 3;  // 2x4 wave grid
    const int m0 = blockIdx.y * 256, n0 = blockIdx.x * 256;

    f32x4 acc[8][4];
#pragma unroll
    for (int i = 0; i < 8; i++)
#pragma unroll
        for (int j = 0; j < 4; j++)
#pragma unroll
            for (int e = 0; e < 4; e++) acc[i][j][e] = 0.0f;

    const int lr = tid >> 2;
    const int c8 = (((lane & 3) ^ ((lane >> 3) & 3)) << 3);
    const ushort_t* Ag = A + (size_t)(m0 + lr) * K + c8;
    const ushort_t* Bg = Bt + (size_t)(n0 + lr) * K + c8;
    ushort_t* Alw = Asb + w * 512;
    ushort_t* Blw = Bsb + w * 512;

    auto stage = [&](int t, int buf) {
        const int k0 = t * 32;
        const ushort_t* ag = Ag + k0;
        const ushort_t* bg = Bg + k0;
        ushort_t* la = Alw + buf * 8192;
        ushort_t* lb = Blw + buf * 8192;
        load_lds16(ag, la);
        load_lds16(ag + (size_t)128 * K, la + 4096);
        load_lds16(bg, lb);
        load_lds16(bg + (size_t)128 * K, lb + 4096);
    };

    const int rsw = (l16 >> 1) & 3;  // reader swizzle
    const int aoff = (wr * 128 + l16) * 32 + ((quad ^ rsw) << 3);
    const int boff = (wc * 16 + l16) * 32 + ((quad ^ rsw) << 3);

    auto compute = [&](int buf) {
        const ushort_t* Ab = Asb + buf * 8192 + aoff;
        const ushort_t* Bb = Bsb + buf * 8192 + boff;
        bf16x8 bfr[4], af[8];
#pragma unroll
        for (int j = 0; j < 4; j++) bfr[j] = *(const bf16x8*)&Bb[j * 2048];  // col tile wc+4j
#pragma unroll
        for (int i = 0; i < 8; i++) af[i] = *(const bf16x8*)&Ab[i * 512];
        __builtin_amdgcn_s_setprio(1);
#pragma unroll
        for (int i = 0; i < 8; i++)
#pragma unroll
            for (int j = 0; j < 4; j++) acc[i][j] = mfma16(af[i], bfr[j], acc[i][j]);
        __builtin_amdgcn_s_setprio(0);
    };

    const int nt = K >> 5;  // K-tiles of 32
    stage(0, 0);
    stage(1, 1);
    int cur = 0, nx = 2;
    for (int t = 0; t < nt - 2; ++t) {
        stage(t + 2, nx);
        asm volatile("s_waitcnt vmcnt(8)" ::: "memory");  // tile t landed; t+1,t+2 in flight
        __builtin_amdgcn_s_barrier();
        __builtin_amdgcn_sched_barrier(0);
        compute(cur);
        __builtin_amdgcn_sched_barrier(0);
        __builtin_amdgcn_s_barrier();
        cur = (cur == 2) ? 0 : cur + 1;
        nx = (nx == 2) ? 0 : nx + 1;
    }
    asm volatile("s_waitcnt vmcnt(4)" ::: "memory");
    __builtin_amdgcn_s_barrier();
    __builtin_amdgcn_sched_barrier(0);
    compute(cur);
    __builtin_amdgcn_sched_barrier(0);
    __builtin_amdgcn_s_barrier();
    cur = (cur == 2) ? 0 : cur + 1;
    asm volatile("s_waitcnt vmcnt(0)" ::: "memory");
    __builtin_amdgcn_s_barrier();
    __builtin_amdgcn_sched_barrier(0);
    compute(cur);

    // ---- epilogues ----
    if (MODE == 0) {
        float* O = (float*)out;
#pragma unroll
        for (int i = 0; i < 8; i++)
#pragma unroll
            for (int r = 0; r < 4; r++) {
                int row = m0 + wr * 128 + i * 16 + quad * 4 + r;
#pragma unroll
                for (int j = 0; j < 4; j++) {
                    int col = n0 + (wc + 4 * j) * 16 + l16;
                    O[(size_t)row * N + col] = acc[i][j][r] + bias[col];
                }
            }
    } else {  // MODE 2: fused QKV
        if (n0 < 2048) {  // Q path: RoPE + scale; block covers heads h0, h0+1
            ushort_t* O = (ushort_t*)out;
            const int h0 = n0 >> 7;
            const float scale = 0.08838834764831845f;
            const int dl = wc * 16 + l16;  // 0..63, same for both heads
            const float fr = __expf(-0.21586735246819178f * (float)dl);
#pragma unroll
            for (int i = 0; i < 8; i++)
#pragma unroll
                for (int r = 0; r < 4; r++) {
                    int row = m0 + wr * 128 + i * 16 + quad * 4 + r;  // b*SEQ + s
                    int b = row >> 11, s = row & (SEQ - 1);
                    float pos = (float)posids[row];
                    float sn, cs;
                    __sincosf(pos * fr, &sn, &cs);
#pragma unroll
                    for (int p = 0; p < 2; p++) {
                        float x1 = acc[i][2 * p][r] + bias[n0 + p * 128 + dl];
                        float x2 = acc[i][2 * p + 1][r] + bias[n0 + p * 128 + dl + 64];
                        size_t obase = ((size_t)(b * NH + h0 + p) * SEQ + s) * HD;
                        O[obase + dl]      = f2bf((x1 * cs - x2 * sn) * scale);
                        O[obase + dl + 64] = f2bf((x2 * cs + x1 * sn) * scale);
                    }
                }
        } else if (n0 < 2560) {  // K path: RoPE; block covers kv-heads h0, h0+1
            ushort_t* O = (ushort_t*)out2;
            const int n0k = n0 - 2048;
            const int h0 = n0k >> 7;
            const int dl = wc * 16 + l16;
            const float fr = __expf(-0.21586735246819178f * (float)dl);
#pragma unroll
            for (int i = 0; i < 8; i++)
#pragma unroll
                for (int r = 0; r < 4; r++) {
                    int row = m0 + wr * 128 + i * 16 + quad * 4 + r;
                    int b = row >> 11, s = row & (SEQ - 1);
                    float pos = (float)posids[row];
                    float sn, cs;
                    __sincosf(pos * fr, &sn, &cs);
#pragma unroll
                    for (int p = 0; p < 2; p++) {
                        float x1 = acc[i][2 * p][r] + bias2[n0k + p * 128 + dl];
                        float x2 = acc[i][2 * p + 1][r] + bias2[n0k + p * 128 + dl + 64];
                        size_t obase = ((size_t)(b * NKV + h0 + p) * SEQ + s) * HD;
                        O[obase + dl]      = f2bf(x1 * cs - x2 * sn);
                        O[obase + dl + 64] = f2bf(x2 * cs + x1 * sn);
                    }
                }
        } else {  // V path: transposed store
            ushort_t* O = (ushort_t*)out3;
            const int n0v = n0 - 2560;
#pragma unroll
            for (int i = 0; i < 8; i++)
#pragma unroll
                for (int r = 0; r < 4; r++) {
                    int row = m0 + wr * 128 + i * 16 + quad * 4 + r;
                    int b = row >> 11, s = row & (SEQ - 1);
#pragma unroll
                    for (int j = 0; j < 4; j++) {
                        int ct = wc + 4 * j;                     // 0..15
                        int h = (n0v >> 7) + (ct >> 3);          // kv head
                        int d = (ct & 7) * 16 + l16;             // head dim 0..127
                        float v = acc[i][j][r] + bias3[n0v + ct * 16 + l16];
                        O[((size_t)(b * NKV + h) * HD + d) * SEQ + s] = f2bf(v);
                    }
                }
        }
    }
}

// ---------------- causal GQA flash attention, Q128, staged K+V, counted-vmcnt ----------------
// Qr [B][NH][S][HD], Kr [B][NKV][S][HD], Vt [B][NKV][HD][S] -> Attn bf16 [B*S][HIDDEN]
// 128 q-rows per block (2 subtiles of 64); kv-tile = 64. K,V double-buffered in LDS.
// Loop: stage(next); s_waitcnt vmcnt(8); s_barrier; compute; s_barrier — next-tile
// loads stay in flight across compute (no vmcnt-0 drain in the loop body).
__global__ __launch_bounds__(256) void flash(const ushort_t* __restrict__ Qr,
                                             const ushort_t* __restrict__ Kr,
                                             const ushort_t* __restrict__ Vt,
                                             ushort_t* __restrict__ Attn) {
    __shared__ __align__(16) ushort_t Ksh[2 * 4 * 64 * 32];   // 32 KB
    __shared__ __align__(16) ushort_t Vsh[2 * 2 * 128 * 32];  // 32 KB
    __shared__ __align__(16) ushort_t Ps[4 * 16 * 72];        // 9 KB, per-wave
    const int tid = threadIdx.x;
    const int w = tid >> 6, lane = tid & 63, quad = lane >> 4, l16 = lane & 15;
    const int x = blockIdx.x, h = blockIdx.y, b = blockIdx.z;
    // pair-balance: co-resident blocks L and L+256 differ only in b -> qt sums constant
    const int qt = b ? x : (gridDim.x - 1 - x);
    const int q0 = qt * 128;
    const int nkt = 2 * qt + 2;
    const int hkv = h >> 2;
    const ushort_t* Kg = Kr + ((size_t)(b * NKV + hkv) * SEQ) * HD;
    const ushort_t* Vg = Vt + ((size_t)(b * NKV + hkv) * HD) * SEQ;

    const int p = lane >> 2;
    const int gc8 = (((lane & 3) ^ ((lane >> 3) & 3)) << 3);
    const ushort_t* kst = Kg + (size_t)p * HD + w * 32 + gc8;
    const ushort_t* vst = Vg + (size_t)((w & 1) * 64 + p) * SEQ + (w >> 1) * 32 + gc8;
    ushort_t* ksl = Ksh + w * 2048;
    ushort_t* vsl = Vsh + (w >> 1) * 4096 + (w & 1) * 2048;

    auto stage = [&](int bi, int kv0) {
        const ushort_t* gk = kst + (size_t)kv0 * HD;
        ushort_t* lk = ksl + bi * 8192;
        load_lds16(gk, lk);
        load_lds16(gk + (size_t)16 * HD, lk + 512);
        load_lds16(gk + (size_t)32 * HD, lk + 1024);
        load_lds16(gk + (size_t)48 * HD, lk + 1536);
        const ushort_t* gv = vst + kv0;
        ushort_t* lv = vsl + bi * 8192;
        load_lds16(gv, lv);
        load_lds16(gv + (size_t)16 * SEQ, lv + 512);
        load_lds16(gv + (size_t)32 * SEQ, lv + 1024);
        load_lds16(gv + (size_t)48 * SEQ, lv + 1536);
    };

    // Q fragments in registers: 2 subtiles x 4 k-chunks
    bf16x8 aq[2][4];
#pragma unroll
    for (int st = 0; st < 2; st++) {
        const size_t qrow = ((size_t)(b * NH + h) * SEQ + q0 + st * 64 + w * 16 + l16) * HD;
#pragma unroll
        for (int kc = 0; kc < 4; kc++)
            aq[st][kc] = *(const bf16x8*)&Qr[qrow + kc * 32 + quad * 8];
    }

    f32x4 o[2][8];
#pragma unroll
    for (int st = 0; st < 2; st++)
#pragma unroll
        for (int j = 0; j < 8; j++)
#pragma unroll
            for (int e = 0; e < 4; e++) o[st][j][e] = 0.0f;
    f32x4 ls2[2];
#pragma unroll
    for (int st = 0; st < 2; st++)
        for (int e = 0; e < 4; e++) ls2[st][e] = 0.0f;
    bf16x8 ones;
#pragma unroll
    for (int e = 0; e < 8; e++) ones[e] = (short)0x3F80;  // bf16 1.0

    ushort_t* Pw = &Ps[w * 16 * 72];
    const int rsw8 = ((l16 >> 1) & 3) << 3;  // reader swizzle (shorts), XOR with quad*8

    stage(0, 0);
    asm volatile("s_waitcnt vmcnt(0)" ::: "memory");
    __builtin_amdgcn_s_barrier();

    for (int kt = 0; kt < nkt; kt++) {
        const int kv0 = kt * 64;
        const int cur = kt & 1;
        if (kt + 1 < nkt) {
            stage(cur ^ 1, kv0 + 64);  // async prefetch next tile
            asm volatile("s_waitcnt vmcnt(8)" ::: "memory");  // tile kt landed; kt+1 in flight
        } else {
            asm volatile("s_waitcnt vmcnt(0)" ::: "memory");
        }
        __builtin_amdgcn_s_barrier();  // all waves' tile-kt staging visible

        const ushort_t* Kb = Ksh + cur * 8192;
        const ushort_t* Vb = Vsh + cur * 8192;

#pragma unroll
        for (int st = 0; st < 2; st++) {
            // subtile 0 is fully masked on the last (odd-diagonal) tile
            if (st == 0 && kt == 2 * qt + 1) continue;

            // QK^T
            f32x4 sa[4];
#pragma unroll
            for (int nt = 0; nt < 4; nt++)
#pragma unroll
                for (int e = 0; e < 4; e++) sa[nt][e] = 0.0f;
#pragma unroll
            for (int kc = 0; kc < 4; kc++) {
#pragma unroll
                for (int nt = 0; nt < 4; nt++) {
                    bf16x8 bk = *(const bf16x8*)&Kb[kc * 2048 + nt * 512 + l16 * 32 +
                                                    ((quad * 8) ^ rsw8)];
                    sa[nt] = mfma16(aq[st][kc], bk, sa[nt]);
                }
            }

            // causal mask on the diagonal tile of this subtile
            if ((kt >> 1) == qt && (kt & 1) == st) {
#pragma unroll
                for (int nt = 0; nt < 4; nt++)
#pragma unroll
                    for (int r = 0; r < 4; r++) {
                        int kvg = kv0 + nt * 16 + l16;
                        int qg = q0 + st * 64 + w * 16 + quad * 4 + r;
                        if (kvg > qg) sa[nt][r] = -1e30f;
                    }
            }

            // P = exp(s), bf16-truncate, per-wave LDS round-trip (C-layout -> A-layout)
#pragma unroll
            for (int nt = 0; nt < 4; nt++)
#pragma unroll
                for (int r = 0; r < 4; r++)
                    Pw[(quad * 4 + r) * 72 + nt * 16 + l16] = f2bf_trunc(__expf(sa[nt][r]));

            // PV
#pragma unroll
            for (int kc = 0; kc < 2; kc++) {
                bf16x8 ap = *(const bf16x8*)&Pw[l16 * 72 + kc * 32 + quad * 8];
                ls2[st] = mfma16(ap, ones, ls2[st]);  // row sums
#pragma unroll
                for (int j = 0; j < 8; j++) {
                    bf16x8 bv = *(const bf16x8*)&Vb[kc * 4096 + (j * 16 + l16) * 32 +
                                                    ((quad * 8) ^ rsw8)];
                    o[st][j] = mfma16(ap, bv, o[st][j]);
                }
            }
        }
        asm volatile("s_barrier" ::: "memory");  // guard buffer reuse by next stage
    }

#pragma unroll
    for (int st = 0; st < 2; st++)
#pragma unroll
        for (int r = 0; r < 4; r++) {
            float inv = 1.0f / ls2[st][r];
            int row = b * SEQ + q0 + st * 64 + w * 16 + quad * 4 + r;
            size_t obase = (size_t)row * HIDDEN + h * HD;
#pragma unroll
            for (int j = 0; j < 8; j++) Attn[obase + j * 16 + l16] = f2bf(o[st][j][r] * inv);
        }
}

extern "C" void kernel_launch(void* const* d_in, const int* in_sizes, int n_in,
                              void* d_out, int out_size, void* d_ws, size_t ws_size,
                              hipStream_t stream) {
    const float* hs = (const float*)d_in[0];
    const int* posids = (const int*)d_in[1];
    const float* Wq = (const float*)d_in[2];
    const float* bq = (const float*)d_in[3];
    const float* Wk = (const float*)d_in[4];
    const float* bk = (const float*)d_in[5];
    const float* Wv = (const float*)d_in[6];
    const float* bv = (const float*)d_in[7];
    const float* Wo = (const float*)d_in[8];
    const float* bo = (const float*)d_in[9];
    float* out = (float*)d_out;

    char* ws = (char*)d_ws;
    size_t off = 0;
    auto alloc = [&](size_t bytes) {
        char* p = ws + off;
        off += (bytes + 255) & ~(size_t)255;
        return p;
    };
    ushort_t* Xb     = (ushort_t*)alloc(4096ull * 2048 * 2);
    ushort_t* WqkvT  = (ushort_t*)alloc(3072ull * 2048 * 2);
    ushort_t* WoT    = (ushort_t*)alloc(2048ull * 2048 * 2);
    ushort_t* Qr     = (ushort_t*)alloc((size_t)BATCH * NH * SEQ * HD * 2);
    ushort_t* Kr     = (ushort_t*)alloc((size_t)BATCH * NKV * SEQ * HD * 2);
    ushort_t* Vtr    = (ushort_t*)alloc((size_t)BATCH * NKV * HD * SEQ * 2);
    ushort_t* Attn   = (ushort_t*)alloc(4096ull * 2048 * 2);

    convert_x<<<4096 * 2048 / 4 / 256, 256, 0, stream>>>(hs, Xb, 4096 * 2048 / 4);
    transpose_all<<<dim3(32, 32, 4), 256, 0, stream>>>(Wq, Wk, Wv, Wo, WqkvT, WoT);

    gemm256<2><<<dim3(12, 16), 512, 0, stream>>>(Xb, WqkvT, bq, bk, bv,
                                                 Qr, Kr, Vtr, 4096, 3072, 2048, posids);

    flash<<<dim3(SEQ / 128, NH, BATCH), 256, 0, stream>>>(Qr, Kr, Vtr, Attn);

    gemm256<0><<<dim3(8, 16), 512, 0, stream>>>(Attn, WoT, bo, nullptr, nullptr,
                                                out, nullptr, nullptr, 4096, 2048, 2048, nullptr);
}

// Round 5
// 343.738 us; speedup vs baseline: 1.2729x; 1.0646x over previous
//
#include <hip/hip_runtime.h>
#include <cmath>

#define HIDDEN 2048
#define NH 16
#define NKV 4
#define HD 128
#define SEQ 2048
#define BATCH 2

typedef unsigned short ushort_t;
typedef short bf16x8 __attribute__((ext_vector_type(8)));
typedef float f32x4 __attribute__((ext_vector_type(4)));
typedef ushort_t u16x4 __attribute__((ext_vector_type(4)));

__device__ __forceinline__ ushort_t f2bf(float f) {
    union { float f; unsigned int u; } v; v.f = f;
    unsigned int r = v.u + 0x7fffu + ((v.u >> 16) & 1u);
    return (ushort_t)(r >> 16);
}
__device__ __forceinline__ ushort_t f2bf_trunc(float f) {
    union { float f; unsigned int u; } v; v.f = f;
    return (ushort_t)(v.u >> 16);
}

__device__ __forceinline__ f32x4 mfma16(bf16x8 a, bf16x8 b, f32x4 c) {
    return __builtin_amdgcn_mfma_f32_16x16x32_bf16(a, b, c, 0, 0, 0);
}

// async global -> LDS, 16B per lane. LDS dst is wave-uniform base + lane*16.
__device__ __forceinline__ void load_lds16(const void* g, void* l) {
    __builtin_amdgcn_global_load_lds((const __attribute__((address_space(1))) unsigned int*)g,
                                     (__attribute__((address_space(3))) unsigned int*)l,
                                     16, 0, 0);
}

// ---------------- elementwise fp32 -> bf16 ----------------
__global__ __launch_bounds__(256) void convert_x(const float* __restrict__ x,
                                                 ushort_t* __restrict__ xb, int n4) {
    int g = blockIdx.x * 256 + threadIdx.x;
    if (g >= n4) return;
    float4 v = ((const float4*)x)[g];
    u16x4 o;
    o[0] = f2bf(v.x); o[1] = f2bf(v.y); o[2] = f2bf(v.z); o[3] = f2bf(v.w);
    ((u16x4*)xb)[g] = o;
}

// ---------------- all weights: W [K][N] fp32 -> WT [N][K] bf16, one launch ----------------
__global__ __launch_bounds__(256) void transpose_all(const float* __restrict__ Wq,
                                                     const float* __restrict__ Wk,
                                                     const float* __restrict__ Wv,
                                                     const float* __restrict__ Wo,
                                                     ushort_t* __restrict__ WqkvT,
                                                     ushort_t* __restrict__ WoT) {
    const int z = blockIdx.z;
    const float* W;
    ushort_t* WT;
    int N;
    if (z == 0)      { W = Wq; WT = WqkvT;                        N = 2048; }
    else if (z == 1) { W = Wk; WT = WqkvT + 2048ull * 2048;       N = 512;  }
    else if (z == 2) { W = Wv; WT = WqkvT + 2560ull * 2048;       N = 512;  }
    else             { W = Wo; WT = WoT;                          N = 2048; }
    const int K = 2048;
    const int n0 = blockIdx.x * 64, k0 = blockIdx.y * 64;
    if (n0 >= N) return;
    __shared__ ushort_t T[64][72];
    const int t = threadIdx.x;
    for (int idx = t; idx < 64 * 16; idx += 256) {
        int r = idx >> 4, c4 = (idx & 15) << 2;
        float4 v = *(const float4*)&W[(size_t)(k0 + r) * N + n0 + c4];
        T[r][c4 + 0] = f2bf(v.x); T[r][c4 + 1] = f2bf(v.y);
        T[r][c4 + 2] = f2bf(v.z); T[r][c4 + 3] = f2bf(v.w);
    }
    __syncthreads();
    for (int idx = t; idx < 64 * 16; idx += 256) {
        int n = idx >> 4, kg = (idx & 15) << 2;
        u16x4 o;
        o[0] = T[kg + 0][n]; o[1] = T[kg + 1][n];
        o[2] = T[kg + 2][n]; o[3] = T[kg + 3][n];
        *(u16x4*)&WT[(size_t)(n0 + n) * K + k0 + kg] = o;
    }
}

// ---------------- 256x256-tile GEMM, 8-phase counted-vmcnt schedule ----------------
// C = A[M][K] * Bt[N][K]^T + bias, fused epilogues.
// 512 threads = 8 waves (2 row x 4 col); per-wave output 128x64 (acc[8][4]).
// BK=64, full 2-tile double buffer (128 KiB LDS).  Per K-tile u: 4 phases
//   P1: read a[0..7](kc0)+b01(kc0); stage A0(u+1); vmcnt(2); bar; 16 MFMA; bar
//   P2: read b23(kc0);              stage A1(u+1);           bar; 16 MFMA; bar
//   P3: read a[0..7](kc1)+b01(kc1); stage B0(u+1);           bar; 16 MFMA; bar
//   P4: read b23(kc1);              stage B1(u+1); vmcnt(2); bar; 16 MFMA; bar
// In-flight accounting (2 loads/thread per stage): vmcnt(2) at P1 covers B1(u)
// (needed P2); vmcnt(2) at P4 covers A0,A1,B0(u+1) (needed next P1). Loads are
// never drained to 0 until the last tile.
// LDS layout: [256 rows][64 shorts]; slot swizzle g=(kc^(row&1))*4 + (c^((row>>1)&3))
// (16B slots) -> conflict-free ds_read_b128; global_load_lds source uses the inverse
// per-lane permutation (kh=((l>>2)&1)^((l>>3)&1), c=(l&3)^((l>>4)&3)).
// Column tiles per wave INTERLEAVED {wc, wc+4, wc+8, wc+12} (RoPE pair in-wave).
template <int MODE>
__global__ __launch_bounds__(512) void gemm256(const ushort_t* __restrict__ A,
                                               const ushort_t* __restrict__ Bt,
                                               const float* __restrict__ bias,
                                               const float* __restrict__ bias2,
                                               const float* __restrict__ bias3,
                                               void* __restrict__ out,
                                               void* __restrict__ out2,
                                               void* __restrict__ out3,
                                               int M, int N, int K,
                                               const int* __restrict__ posids) {
    __shared__ __align__(16) ushort_t Asb[2][16384];  // 2 x (256 rows x 64 shorts) = 64 KB
    __shared__ __align__(16) ushort_t Bsb[2][16384];  // 64 KB
    const int tid = threadIdx.x;
    const int w = tid >> 6, lane = tid & 63, quad = lane >> 4, l16 = lane & 15;
    const int wr = w >> 2, wc = w & 3;  // 2x4 wave grid
    const int m0 = blockIdx.y * 256, n0 = blockIdx.x * 256;

    f32x4 acc[8][4];
#pragma unroll
    for (int i = 0; i < 8; i++)
#pragma unroll
        for (int j = 0; j < 4; j++)
#pragma unroll
            for (int e = 0; e < 4; e++) acc[i][j][e] = 0.0f;

    // staging source permutation (per-lane constant)
    const int lrow = lane >> 3;  // 0..7 within the 8-row block
    const int kh_s = ((lane >> 2) & 1) ^ ((lane >> 3) & 1);
    const int c_s  = (lane & 3) ^ ((lane >> 4) & 3);
    const int scol = kh_s * 32 + c_s * 8;  // shorts within the K-tile's 64 cols

    auto stageA = [&](int t, int buf, int ha) {
        const ushort_t* g = A + (size_t)(m0 + ha * 128 + w * 16 + lrow) * K + t * 64 + scol;
        ushort_t* l = &Asb[buf][(ha * 128 + w * 16) * 64];
        load_lds16(g, l);
        load_lds16(g + (size_t)8 * K, l + 512);
    };
    auto stageB = [&](int t, int buf, int ha) {
        const ushort_t* g = Bt + (size_t)(n0 + ha * 128 + w * 16 + lrow) * K + t * 64 + scol;
        ushort_t* l = &Bsb[buf][(ha * 128 + w * 16) * 64];
        load_lds16(g, l);
        load_lds16(g + (size_t)8 * K, l + 512);
    };

    // reader offsets (shorts): off(kc) = (kc^(l16&1))*32 + (quad^((l16>>1)&3))*8
    const int sw = (quad ^ ((l16 >> 1) & 3)) * 8;
    const int off0 = ((l16 & 1) ? 32 : 0) + sw;       // kc = 0
    const int off1 = ((l16 & 1) ? 0 : 32) + sw;       // kc = 1
    const int arow = (wr * 128 + l16) * 64;           // + i*1024
    const int brow = (wc * 16 + l16) * 64;            // + j*4096

    const int nt = K >> 6;  // 32 K-tiles of 64

    // prologue: stage tile 0 fully; A0,A1,B0 must land (B1 waited at P1)
    stageA(0, 0, 0); stageA(0, 0, 1); stageB(0, 0, 0); stageB(0, 0, 1);
    asm volatile("s_waitcnt vmcnt(2)" ::: "memory");
    __builtin_amdgcn_s_barrier();
    __builtin_amdgcn_sched_barrier(0);

    bf16x8 a[8];
    for (int u = 0; u < nt; ++u) {
        const int bu = u & 1, bn = bu ^ 1;
        const bool pf = (u + 1 < nt);
        const ushort_t* Ab = Asb[bu];
        const ushort_t* Bb = Bsb[bu];

        // ---- P1: kc=0, j={0,1} ----
#pragma unroll
        for (int i = 0; i < 8; i++) a[i] = *(const bf16x8*)&Ab[arow + i * 1024 + off0];
        bf16x8 b0 = *(const bf16x8*)&Bb[brow + off0];
        bf16x8 b1 = *(const bf16x8*)&Bb[brow + 4096 + off0];
        if (pf) { stageA(u + 1, bn, 0); asm volatile("s_waitcnt vmcnt(2)" ::: "memory"); }
        else    { asm volatile("s_waitcnt vmcnt(0)" ::: "memory"); }
        __builtin_amdgcn_s_barrier();
        __builtin_amdgcn_sched_barrier(0);
        __builtin_amdgcn_s_setprio(1);
#pragma unroll
        for (int i = 0; i < 8; i++) {
            acc[i][0] = mfma16(a[i], b0, acc[i][0]);
            acc[i][1] = mfma16(a[i], b1, acc[i][1]);
        }
        __builtin_amdgcn_s_setprio(0);
        __builtin_amdgcn_sched_barrier(0);
        __builtin_amdgcn_s_barrier();
        __builtin_amdgcn_sched_barrier(0);

        // ---- P2: kc=0, j={2,3} ----
        bf16x8 b2 = *(const bf16x8*)&Bb[brow + 8192 + off0];
        bf16x8 b3 = *(const bf16x8*)&Bb[brow + 12288 + off0];
        if (pf) stageA(u + 1, bn, 1);
        __builtin_amdgcn_s_barrier();
        __builtin_amdgcn_sched_barrier(0);
        __builtin_amdgcn_s_setprio(1);
#pragma unroll
        for (int i = 0; i < 8; i++) {
            acc[i][2] = mfma16(a[i], b2, acc[i][2]);
            acc[i][3] = mfma16(a[i], b3, acc[i][3]);
        }
        __builtin_amdgcn_s_setprio(0);
        __builtin_amdgcn_sched_barrier(0);
        __builtin_amdgcn_s_barrier();
        __builtin_amdgcn_sched_barrier(0);

        // ---- P3: kc=1, j={0,1} ----
#pragma unroll
        for (int i = 0; i < 8; i++) a[i] = *(const bf16x8*)&Ab[arow + i * 1024 + off1];
        b0 = *(const bf16x8*)&Bb[brow + off1];
        b1 = *(const bf16x8*)&Bb[brow + 4096 + off1];
        if (pf) stageB(u + 1, bn, 0);
        __builtin_amdgcn_s_barrier();
        __builtin_amdgcn_sched_barrier(0);
        __builtin_amdgcn_s_setprio(1);
#pragma unroll
        for (int i = 0; i < 8; i++) {
            acc[i][0] = mfma16(a[i], b0, acc[i][0]);
            acc[i][1] = mfma16(a[i], b1, acc[i][1]);
        }
        __builtin_amdgcn_s_setprio(0);
        __builtin_amdgcn_sched_barrier(0);
        __builtin_amdgcn_s_barrier();
        __builtin_amdgcn_sched_barrier(0);

        // ---- P4: kc=1, j={2,3} ----
        b2 = *(const bf16x8*)&Bb[brow + 8192 + off1];
        b3 = *(const bf16x8*)&Bb[brow + 12288 + off1];
        if (pf) { stageB(u + 1, bn, 1); asm volatile("s_waitcnt vmcnt(2)" ::: "memory"); }
        __builtin_amdgcn_s_barrier();
        __builtin_amdgcn_sched_barrier(0);
        __builtin_amdgcn_s_setprio(1);
#pragma unroll
        for (int i = 0; i < 8; i++) {
            acc[i][2] = mfma16(a[i], b2, acc[i][2]);
            acc[i][3] = mfma16(a[i], b3, acc[i][3]);
        }
        __builtin_amdgcn_s_setprio(0);
        __builtin_amdgcn_sched_barrier(0);
        __builtin_amdgcn_s_barrier();
        __builtin_amdgcn_sched_barrier(0);
    }

    // ---- epilogues (verified r2/r4 decomposition) ----
    if (MODE == 0) {
        float* O = (float*)out;
#pragma unroll
        for (int i = 0; i < 8; i++)
#pragma unroll
            for (int r = 0; r < 4; r++) {
                int row = m0 + wr * 128 + i * 16 + quad * 4 + r;
#pragma unroll
                for (int j = 0; j < 4; j++) {
                    int col = n0 + (wc + 4 * j) * 16 + l16;
                    O[(size_t)row * N + col] = acc[i][j][r] + bias[col];
                }
            }
    } else {  // MODE 2: fused QKV
        if (n0 < 2048) {  // Q path: RoPE + scale; block covers heads h0, h0+1
            ushort_t* O = (ushort_t*)out;
            const int h0 = n0 >> 7;
            const float scale = 0.08838834764831845f;
            const int dl = wc * 16 + l16;  // 0..63, same for both heads
            const float fr = __expf(-0.21586735246819178f * (float)dl);
#pragma unroll
            for (int i = 0; i < 8; i++)
#pragma unroll
                for (int r = 0; r < 4; r++) {
                    int row = m0 + wr * 128 + i * 16 + quad * 4 + r;  // b*SEQ + s
                    int b = row >> 11, s = row & (SEQ - 1);
                    float pos = (float)posids[row];
                    float sn, cs;
                    __sincosf(pos * fr, &sn, &cs);
#pragma unroll
                    for (int p = 0; p < 2; p++) {
                        float x1 = acc[i][2 * p][r] + bias[n0 + p * 128 + dl];
                        float x2 = acc[i][2 * p + 1][r] + bias[n0 + p * 128 + dl + 64];
                        size_t obase = ((size_t)(b * NH + h0 + p) * SEQ + s) * HD;
                        O[obase + dl]      = f2bf((x1 * cs - x2 * sn) * scale);
                        O[obase + dl + 64] = f2bf((x2 * cs + x1 * sn) * scale);
                    }
                }
        } else if (n0 < 2560) {  // K path: RoPE; block covers kv-heads h0, h0+1
            ushort_t* O = (ushort_t*)out2;
            const int n0k = n0 - 2048;
            const int h0 = n0k >> 7;
            const int dl = wc * 16 + l16;
            const float fr = __expf(-0.21586735246819178f * (float)dl);
#pragma unroll
            for (int i = 0; i < 8; i++)
#pragma unroll
                for (int r = 0; r < 4; r++) {
                    int row = m0 + wr * 128 + i * 16 + quad * 4 + r;
                    int b = row >> 11, s = row & (SEQ - 1);
                    float pos = (float)posids[row];
                    float sn, cs;
                    __sincosf(pos * fr, &sn, &cs);
#pragma unroll
                    for (int p = 0; p < 2; p++) {
                        float x1 = acc[i][2 * p][r] + bias2[n0k + p * 128 + dl];
                        float x2 = acc[i][2 * p + 1][r] + bias2[n0k + p * 128 + dl + 64];
                        size_t obase = ((size_t)(b * NKV + h0 + p) * SEQ + s) * HD;
                        O[obase + dl]      = f2bf(x1 * cs - x2 * sn);
                        O[obase + dl + 64] = f2bf(x2 * cs + x1 * sn);
                    }
                }
        } else {  // V path: transposed store
            ushort_t* O = (ushort_t*)out3;
            const int n0v = n0 - 2560;
#pragma unroll
            for (int i = 0; i < 8; i++)
#pragma unroll
                for (int r = 0; r < 4; r++) {
                    int row = m0 + wr * 128 + i * 16 + quad * 4 + r;
                    int b = row >> 11, s = row & (SEQ - 1);
#pragma unroll
                    for (int j = 0; j < 4; j++) {
                        int ct = wc + 4 * j;                     // 0..15
                        int h = (n0v >> 7) + (ct >> 3);          // kv head
                        int d = (ct & 7) * 16 + l16;             // head dim 0..127
                        float v = acc[i][j][r] + bias3[n0v + ct * 16 + l16];
                        O[((size_t)(b * NKV + h) * HD + d) * SEQ + s] = f2bf(v);
                    }
                }
        }
    }
}

// ---------------- causal GQA flash attention, Q128, staged K+V, counted-vmcnt ----------------
// (unchanged from round 4 — passed, <88 us)
__global__ __launch_bounds__(256) void flash(const ushort_t* __restrict__ Qr,
                                             const ushort_t* __restrict__ Kr,
                                             const ushort_t* __restrict__ Vt,
                                             ushort_t* __restrict__ Attn) {
    __shared__ __align__(16) ushort_t Ksh[2 * 4 * 64 * 32];   // 32 KB
    __shared__ __align__(16) ushort_t Vsh[2 * 2 * 128 * 32];  // 32 KB
    __shared__ __align__(16) ushort_t Ps[4 * 16 * 72];        // 9 KB, per-wave
    const int tid = threadIdx.x;
    const int w = tid >> 6, lane = tid & 63, quad = lane >> 4, l16 = lane & 15;
    const int x = blockIdx.x, h = blockIdx.y, b = blockIdx.z;
    const int qt = b ? x : (gridDim.x - 1 - x);
    const int q0 = qt * 128;
    const int nkt = 2 * qt + 2;
    const int hkv = h >> 2;
    const ushort_t* Kg = Kr + ((size_t)(b * NKV + hkv) * SEQ) * HD;
    const ushort_t* Vg = Vt + ((size_t)(b * NKV + hkv) * HD) * SEQ;

    const int p = lane >> 2;
    const int gc8 = (((lane & 3) ^ ((lane >> 3) & 3)) << 3);
    const ushort_t* kst = Kg + (size_t)p * HD + w * 32 + gc8;
    const ushort_t* vst = Vg + (size_t)((w & 1) * 64 + p) * SEQ + (w >> 1) * 32 + gc8;
    ushort_t* ksl = Ksh + w * 2048;
    ushort_t* vsl = Vsh + (w >> 1) * 4096 + (w & 1) * 2048;

    auto stage = [&](int bi, int kv0) {
        const ushort_t* gk = kst + (size_t)kv0 * HD;
        ushort_t* lk = ksl + bi * 8192;
        load_lds16(gk, lk);
        load_lds16(gk + (size_t)16 * HD, lk + 512);
        load_lds16(gk + (size_t)32 * HD, lk + 1024);
        load_lds16(gk + (size_t)48 * HD, lk + 1536);
        const ushort_t* gv = vst + kv0;
        ushort_t* lv = vsl + bi * 8192;
        load_lds16(gv, lv);
        load_lds16(gv + (size_t)16 * SEQ, lv + 512);
        load_lds16(gv + (size_t)32 * SEQ, lv + 1024);
        load_lds16(gv + (size_t)48 * SEQ, lv + 1536);
    };

    bf16x8 aq[2][4];
#pragma unroll
    for (int st = 0; st < 2; st++) {
        const size_t qrow = ((size_t)(b * NH + h) * SEQ + q0 + st * 64 + w * 16 + l16) * HD;
#pragma unroll
        for (int kc = 0; kc < 4; kc++)
            aq[st][kc] = *(const bf16x8*)&Qr[qrow + kc * 32 + quad * 8];
    }

    f32x4 o[2][8];
#pragma unroll
    for (int st = 0; st < 2; st++)
#pragma unroll
        for (int j = 0; j < 8; j++)
#pragma unroll
            for (int e = 0; e < 4; e++) o[st][j][e] = 0.0f;
    f32x4 ls2[2];
#pragma unroll
    for (int st = 0; st < 2; st++)
        for (int e = 0; e < 4; e++) ls2[st][e] = 0.0f;
    bf16x8 ones;
#pragma unroll
    for (int e = 0; e < 8; e++) ones[e] = (short)0x3F80;  // bf16 1.0

    ushort_t* Pw = &Ps[w * 16 * 72];
    const int rsw8 = ((l16 >> 1) & 3) << 3;

    stage(0, 0);
    asm volatile("s_waitcnt vmcnt(0)" ::: "memory");
    __builtin_amdgcn_s_barrier();

    for (int kt = 0; kt < nkt; kt++) {
        const int kv0 = kt * 64;
        const int cur = kt & 1;
        if (kt + 1 < nkt) {
            stage(cur ^ 1, kv0 + 64);
            asm volatile("s_waitcnt vmcnt(8)" ::: "memory");
        } else {
            asm volatile("s_waitcnt vmcnt(0)" ::: "memory");
        }
        __builtin_amdgcn_s_barrier();

        const ushort_t* Kb = Ksh + cur * 8192;
        const ushort_t* Vb = Vsh + cur * 8192;

#pragma unroll
        for (int st = 0; st < 2; st++) {
            if (st == 0 && kt == 2 * qt + 1) continue;

            f32x4 sa[4];
#pragma unroll
            for (int nt = 0; nt < 4; nt++)
#pragma unroll
                for (int e = 0; e < 4; e++) sa[nt][e] = 0.0f;
#pragma unroll
            for (int kc = 0; kc < 4; kc++) {
#pragma unroll
                for (int nt = 0; nt < 4; nt++) {
                    bf16x8 bk = *(const bf16x8*)&Kb[kc * 2048 + nt * 512 + l16 * 32 +
                                                    ((quad * 8) ^ rsw8)];
                    sa[nt] = mfma16(aq[st][kc], bk, sa[nt]);
                }
            }

            if ((kt >> 1) == qt && (kt & 1) == st) {
#pragma unroll
                for (int nt = 0; nt < 4; nt++)
#pragma unroll
                    for (int r = 0; r < 4; r++) {
                        int kvg = kv0 + nt * 16 + l16;
                        int qg = q0 + st * 64 + w * 16 + quad * 4 + r;
                        if (kvg > qg) sa[nt][r] = -1e30f;
                    }
            }

#pragma unroll
            for (int nt = 0; nt < 4; nt++)
#pragma unroll
                for (int r = 0; r < 4; r++)
                    Pw[(quad * 4 + r) * 72 + nt * 16 + l16] = f2bf_trunc(__expf(sa[nt][r]));

#pragma unroll
            for (int kc = 0; kc < 2; kc++) {
                bf16x8 ap = *(const bf16x8*)&Pw[l16 * 72 + kc * 32 + quad * 8];
                ls2[st] = mfma16(ap, ones, ls2[st]);
#pragma unroll
                for (int j = 0; j < 8; j++) {
                    bf16x8 bv = *(const bf16x8*)&Vb[kc * 4096 + (j * 16 + l16) * 32 +
                                                    ((quad * 8) ^ rsw8)];
                    o[st][j] = mfma16(ap, bv, o[st][j]);
                }
            }
        }
        asm volatile("s_barrier" ::: "memory");
    }

#pragma unroll
    for (int st = 0; st < 2; st++)
#pragma unroll
        for (int r = 0; r < 4; r++) {
            float inv = 1.0f / ls2[st][r];
            int row = b * SEQ + q0 + st * 64 + w * 16 + quad * 4 + r;
            size_t obase = (size_t)row * HIDDEN + h * HD;
#pragma unroll
            for (int j = 0; j < 8; j++) Attn[obase + j * 16 + l16] = f2bf(o[st][j][r] * inv);
        }
}

extern "C" void kernel_launch(void* const* d_in, const int* in_sizes, int n_in,
                              void* d_out, int out_size, void* d_ws, size_t ws_size,
                              hipStream_t stream) {
    const float* hs = (const float*)d_in[0];
    const int* posids = (const int*)d_in[1];
    const float* Wq = (const float*)d_in[2];
    const float* bq = (const float*)d_in[3];
    const float* Wk = (const float*)d_in[4];
    const float* bk = (const float*)d_in[5];
    const float* Wv = (const float*)d_in[6];
    const float* bv = (const float*)d_in[7];
    const float* Wo = (const float*)d_in[8];
    const float* bo = (const float*)d_in[9];
    float* out = (float*)d_out;

    char* ws = (char*)d_ws;
    size_t off = 0;
    auto alloc = [&](size_t bytes) {
        char* p = ws + off;
        off += (bytes + 255) & ~(size_t)255;
        return p;
    };
    ushort_t* Xb     = (ushort_t*)alloc(4096ull * 2048 * 2);
    ushort_t* WqkvT  = (ushort_t*)alloc(3072ull * 2048 * 2);
    ushort_t* WoT    = (ushort_t*)alloc(2048ull * 2048 * 2);
    ushort_t* Qr     = (ushort_t*)alloc((size_t)BATCH * NH * SEQ * HD * 2);
    ushort_t* Kr     = (ushort_t*)alloc((size_t)BATCH * NKV * SEQ * HD * 2);
    ushort_t* Vtr    = (ushort_t*)alloc((size_t)BATCH * NKV * HD * SEQ * 2);
    ushort_t* Attn   = (ushort_t*)alloc(4096ull * 2048 * 2);

    convert_x<<<4096 * 2048 / 4 / 256, 256, 0, stream>>>(hs, Xb, 4096 * 2048 / 4);
    transpose_all<<<dim3(32, 32, 4), 256, 0, stream>>>(Wq, Wk, Wv, Wo, WqkvT, WoT);

    gemm256<2><<<dim3(12, 16), 512, 0, stream>>>(Xb, WqkvT, bq, bk, bv,
                                                 Qr, Kr, Vtr, 4096, 3072, 2048, posids);

    flash<<<dim3(SEQ / 128, NH, BATCH), 256, 0, stream>>>(Qr, Kr, Vtr, Attn);

    gemm256<0><<<dim3(8, 16), 512, 0, stream>>>(Attn, WoT, bo, nullptr, nullptr,
                                                out, nullptr, nullptr, 4096, 2048, 2048, nullptr);
}

// Round 6
// 314.899 us; speedup vs baseline: 1.3895x; 1.0916x over previous
//
#include <hip/hip_runtime.h>
#include <cmath>

#define HIDDEN 2048
#define NH 16
#define NKV 4
#define HD 128
#define SEQ 2048
#define BATCH 2

typedef unsigned short ushort_t;
typedef short bf16x8 __attribute__((ext_vector_type(8)));
typedef float f32x4 __attribute__((ext_vector_type(4)));
typedef ushort_t u16x4 __attribute__((ext_vector_type(4)));

__device__ __forceinline__ ushort_t f2bf(float f) {
    union { float f; unsigned int u; } v; v.f = f;
    unsigned int r = v.u + 0x7fffu + ((v.u >> 16) & 1u);
    return (ushort_t)(r >> 16);
}
__device__ __forceinline__ ushort_t f2bf_trunc(float f) {
    union { float f; unsigned int u; } v; v.f = f;
    return (ushort_t)(v.u >> 16);
}

__device__ __forceinline__ f32x4 mfma16(bf16x8 a, bf16x8 b, f32x4 c) {
    return __builtin_amdgcn_mfma_f32_16x16x32_bf16(a, b, c, 0, 0, 0);
}

// async global -> LDS, 16B per lane. LDS dst is wave-uniform base + lane*16.
__device__ __forceinline__ void load_lds16(const void* g, void* l) {
    __builtin_amdgcn_global_load_lds((const __attribute__((address_space(1))) unsigned int*)g,
                                     (__attribute__((address_space(3))) unsigned int*)l,
                                     16, 0, 0);
}

// ---------------- elementwise fp32 -> bf16 ----------------
__global__ __launch_bounds__(256) void convert_x(const float* __restrict__ x,
                                                 ushort_t* __restrict__ xb, int n4) {
    int g = blockIdx.x * 256 + threadIdx.x;
    if (g >= n4) return;
    float4 v = ((const float4*)x)[g];
    u16x4 o;
    o[0] = f2bf(v.x); o[1] = f2bf(v.y); o[2] = f2bf(v.z); o[3] = f2bf(v.w);
    ((u16x4*)xb)[g] = o;
}

// ---------------- all weights: W [K][N] fp32 -> WT [N][K] bf16, one launch ----------------
__global__ __launch_bounds__(256) void transpose_all(const float* __restrict__ Wq,
                                                     const float* __restrict__ Wk,
                                                     const float* __restrict__ Wv,
                                                     const float* __restrict__ Wo,
                                                     ushort_t* __restrict__ WqkvT,
                                                     ushort_t* __restrict__ WoT) {
    const int z = blockIdx.z;
    const float* W;
    ushort_t* WT;
    int N;
    if (z == 0)      { W = Wq; WT = WqkvT;                        N = 2048; }
    else if (z == 1) { W = Wk; WT = WqkvT + 2048ull * 2048;       N = 512;  }
    else if (z == 2) { W = Wv; WT = WqkvT + 2560ull * 2048;       N = 512;  }
    else             { W = Wo; WT = WoT;                          N = 2048; }
    const int K = 2048;
    const int n0 = blockIdx.x * 64, k0 = blockIdx.y * 64;
    if (n0 >= N) return;
    __shared__ ushort_t T[64][72];
    const int t = threadIdx.x;
    for (int idx = t; idx < 64 * 16; idx += 256) {
        int r = idx >> 4, c4 = (idx & 15) << 2;
        float4 v = *(const float4*)&W[(size_t)(k0 + r) * N + n0 + c4];
        T[r][c4 + 0] = f2bf(v.x); T[r][c4 + 1] = f2bf(v.y);
        T[r][c4 + 2] = f2bf(v.z); T[r][c4 + 3] = f2bf(v.w);
    }
    __syncthreads();
    for (int idx = t; idx < 64 * 16; idx += 256) {
        int n = idx >> 4, kg = (idx & 15) << 2;
        u16x4 o;
        o[0] = T[kg + 0][n]; o[1] = T[kg + 1][n];
        o[2] = T[kg + 2][n]; o[3] = T[kg + 3][n];
        *(u16x4*)&WT[(size_t)(n0 + n) * K + k0 + kg] = o;
    }
}

// ---------------- (BM)x256-tile GEMM, 8-phase counted-vmcnt schedule ----------------
// C = A[M][K] * Bt[N][K]^T + bias, fused epilogues.  BMH = BM/128 (2 = r5-verified path).
// 512 threads = 8 waves (2 row x 4 col); per-wave output (64*BMH)x64 (acc[4*BMH][4]).
// BK=64, full 2-tile double buffer.
// BMH=2 stages/phase: P1:A0  P2:A1  P3:B0  P4:B1;  vmcnt(2) at P1 & P4 (8 loads/tile).
// BMH=1 stages/phase: P1:A   P2:B0  P3:B1  P4:—  ;  vmcnt(2) at P1 & P4 (6 loads/tile).
// In-flight accounting (both): each phase's ds_reads touch only data whose landing was
// guaranteed by the PREVIOUS phase's vmcnt+barrier; loads never drain to 0 mid-loop.
// Column tiles per wave INTERLEAVED {wc, wc+4, wc+8, wc+12} (RoPE pair in-wave).
template <int MODE, int BMH>
__global__ __launch_bounds__(512) void gemm256(const ushort_t* __restrict__ A,
                                               const ushort_t* __restrict__ Bt,
                                               const float* __restrict__ bias,
                                               const float* __restrict__ bias2,
                                               const float* __restrict__ bias3,
                                               void* __restrict__ out,
                                               void* __restrict__ out2,
                                               void* __restrict__ out3,
                                               int M, int N, int K,
                                               const int* __restrict__ posids) {
    constexpr int IM = 4 * BMH;  // acc row-fragments per wave
    __shared__ __align__(16) ushort_t Asb[2][BMH * 8192];
    __shared__ __align__(16) ushort_t Bsb[2][16384];
    const int tid = threadIdx.x;
    const int w = tid >> 6, lane = tid & 63, quad = lane >> 4, l16 = lane & 15;
    const int wr = w >> 2, wc = w & 3;  // 2x4 wave grid
    const int m0 = blockIdx.y * (128 * BMH), n0 = blockIdx.x * 256;

    f32x4 acc[IM][4];
#pragma unroll
    for (int i = 0; i < IM; i++)
#pragma unroll
        for (int j = 0; j < 4; j++)
#pragma unroll
            for (int e = 0; e < 4; e++) acc[i][j][e] = 0.0f;

    // staging source permutation (per-lane constant)
    const int lrow = lane >> 3;  // 0..7 within the 8-row block
    const int kh_s = ((lane >> 2) & 1) ^ ((lane >> 3) & 1);
    const int c_s  = (lane & 3) ^ ((lane >> 4) & 3);
    const int scol = kh_s * 32 + c_s * 8;  // shorts within the K-tile's 64 cols

    auto stageA = [&](int t, int buf, int ha) {
        const ushort_t* g = A + (size_t)(m0 + ha * 128 + w * 16 + lrow) * K + t * 64 + scol;
        ushort_t* l = &Asb[buf][(ha * 128 + w * 16) * 64];
        load_lds16(g, l);
        load_lds16(g + (size_t)8 * K, l + 512);
    };
    auto stageB = [&](int t, int buf, int ha) {
        const ushort_t* g = Bt + (size_t)(n0 + ha * 128 + w * 16 + lrow) * K + t * 64 + scol;
        ushort_t* l = &Bsb[buf][(ha * 128 + w * 16) * 64];
        load_lds16(g, l);
        load_lds16(g + (size_t)8 * K, l + 512);
    };

    // reader offsets (shorts): off(kc) = (kc^(l16&1))*32 + (quad^((l16>>1)&3))*8
    const int sw = (quad ^ ((l16 >> 1) & 3)) * 8;
    const int off0 = ((l16 & 1) ? 32 : 0) + sw;       // kc = 0
    const int off1 = ((l16 & 1) ? 0 : 32) + sw;       // kc = 1
    const int arow = (wr * (64 * BMH) + l16) * 64;    // + i*1024
    const int brow = (wc * 16 + l16) * 64;            // + j*4096

    const int nt = K >> 6;  // K-tiles of 64

    // prologue
    stageA(0, 0, 0);
    if constexpr (BMH == 2) stageA(0, 0, 1);
    stageB(0, 0, 0);
    stageB(0, 0, 1);
    asm volatile("s_waitcnt vmcnt(2)" ::: "memory");
    __builtin_amdgcn_s_barrier();
    __builtin_amdgcn_sched_barrier(0);

    bf16x8 a[IM];
    for (int u = 0; u < nt; ++u) {
        const int bu = u & 1, bn = bu ^ 1;
        const bool pf = (u + 1 < nt);
        const ushort_t* Ab = Asb[bu];
        const ushort_t* Bb = Bsb[bu];

        // ---- P1: kc=0, j={0,1} ----
#pragma unroll
        for (int i = 0; i < IM; i++) a[i] = *(const bf16x8*)&Ab[arow + i * 1024 + off0];
        bf16x8 b0 = *(const bf16x8*)&Bb[brow + off0];
        bf16x8 b1 = *(const bf16x8*)&Bb[brow + 4096 + off0];
        if (pf) { stageA(u + 1, bn, 0); asm volatile("s_waitcnt vmcnt(2)" ::: "memory"); }
        else    { asm volatile("s_waitcnt vmcnt(0)" ::: "memory"); }
        __builtin_amdgcn_s_barrier();
        __builtin_amdgcn_sched_barrier(0);
        __builtin_amdgcn_s_setprio(1);
#pragma unroll
        for (int i = 0; i < IM; i++) {
            acc[i][0] = mfma16(a[i], b0, acc[i][0]);
            acc[i][1] = mfma16(a[i], b1, acc[i][1]);
        }
        __builtin_amdgcn_s_setprio(0);
        __builtin_amdgcn_sched_barrier(0);
        __builtin_amdgcn_s_barrier();
        __builtin_amdgcn_sched_barrier(0);

        // ---- P2: kc=0, j={2,3} ----
        bf16x8 b2 = *(const bf16x8*)&Bb[brow + 8192 + off0];
        bf16x8 b3 = *(const bf16x8*)&Bb[brow + 12288 + off0];
        if (pf) {
            if constexpr (BMH == 2) stageA(u + 1, bn, 1);
            else                    stageB(u + 1, bn, 0);
        }
        __builtin_amdgcn_s_barrier();
        __builtin_amdgcn_sched_barrier(0);
        __builtin_amdgcn_s_setprio(1);
#pragma unroll
        for (int i = 0; i < IM; i++) {
            acc[i][2] = mfma16(a[i], b2, acc[i][2]);
            acc[i][3] = mfma16(a[i], b3, acc[i][3]);
        }
        __builtin_amdgcn_s_setprio(0);
        __builtin_amdgcn_sched_barrier(0);
        __builtin_amdgcn_s_barrier();
        __builtin_amdgcn_sched_barrier(0);

        // ---- P3: kc=1, j={0,1} ----
#pragma unroll
        for (int i = 0; i < IM; i++) a[i] = *(const bf16x8*)&Ab[arow + i * 1024 + off1];
        b0 = *(const bf16x8*)&Bb[brow + off1];
        b1 = *(const bf16x8*)&Bb[brow + 4096 + off1];
        if (pf) {
            if constexpr (BMH == 2) stageB(u + 1, bn, 0);
            else                    stageB(u + 1, bn, 1);
        }
        __builtin_amdgcn_s_barrier();
        __builtin_amdgcn_sched_barrier(0);
        __builtin_amdgcn_s_setprio(1);
#pragma unroll
        for (int i = 0; i < IM; i++) {
            acc[i][0] = mfma16(a[i], b0, acc[i][0]);
            acc[i][1] = mfma16(a[i], b1, acc[i][1]);
        }
        __builtin_amdgcn_s_setprio(0);
        __builtin_amdgcn_sched_barrier(0);
        __builtin_amdgcn_s_barrier();
        __builtin_amdgcn_sched_barrier(0);

        // ---- P4: kc=1, j={2,3} ----
        b2 = *(const bf16x8*)&Bb[brow + 8192 + off1];
        b3 = *(const bf16x8*)&Bb[brow + 12288 + off1];
        if (pf) {
            if constexpr (BMH == 2) stageB(u + 1, bn, 1);
            asm volatile("s_waitcnt vmcnt(2)" ::: "memory");
        }
        __builtin_amdgcn_s_barrier();
        __builtin_amdgcn_sched_barrier(0);
        __builtin_amdgcn_s_setprio(1);
#pragma unroll
        for (int i = 0; i < IM; i++) {
            acc[i][2] = mfma16(a[i], b2, acc[i][2]);
            acc[i][3] = mfma16(a[i], b3, acc[i][3]);
        }
        __builtin_amdgcn_s_setprio(0);
        __builtin_amdgcn_sched_barrier(0);
        __builtin_amdgcn_s_barrier();
        __builtin_amdgcn_sched_barrier(0);
    }

    // ---- epilogues ----
    if (MODE == 0) {
        float* O = (float*)out;
#pragma unroll
        for (int i = 0; i < IM; i++)
#pragma unroll
            for (int r = 0; r < 4; r++) {
                int row = m0 + wr * (64 * BMH) + i * 16 + quad * 4 + r;
#pragma unroll
                for (int j = 0; j < 4; j++) {
                    int col = n0 + (wc + 4 * j) * 16 + l16;
                    O[(size_t)row * N + col] = acc[i][j][r] + bias[col];
                }
            }
    } else {  // MODE 2: fused QKV (BMH == 2)
        if (n0 < 2048) {  // Q path: RoPE + scale; block covers heads h0, h0+1
            ushort_t* O = (ushort_t*)out;
            const int h0 = n0 >> 7;
            const float scale = 0.08838834764831845f;
            const int dl = wc * 16 + l16;  // 0..63, same for both heads
            const float fr = __expf(-0.21586735246819178f * (float)dl);
#pragma unroll
            for (int i = 0; i < IM; i++)
#pragma unroll
                for (int r = 0; r < 4; r++) {
                    int row = m0 + wr * (64 * BMH) + i * 16 + quad * 4 + r;  // b*SEQ + s
                    int b = row >> 11, s = row & (SEQ - 1);
                    float pos = (float)posids[row];
                    float sn, cs;
                    __sincosf(pos * fr, &sn, &cs);
#pragma unroll
                    for (int p = 0; p < 2; p++) {
                        float x1 = acc[i][2 * p][r] + bias[n0 + p * 128 + dl];
                        float x2 = acc[i][2 * p + 1][r] + bias[n0 + p * 128 + dl + 64];
                        size_t obase = ((size_t)(b * NH + h0 + p) * SEQ + s) * HD;
                        O[obase + dl]      = f2bf((x1 * cs - x2 * sn) * scale);
                        O[obase + dl + 64] = f2bf((x2 * cs + x1 * sn) * scale);
                    }
                }
        } else if (n0 < 2560) {  // K path: RoPE; block covers kv-heads h0, h0+1
            ushort_t* O = (ushort_t*)out2;
            const int n0k = n0 - 2048;
            const int h0 = n0k >> 7;
            const int dl = wc * 16 + l16;
            const float fr = __expf(-0.21586735246819178f * (float)dl);
#pragma unroll
            for (int i = 0; i < IM; i++)
#pragma unroll
                for (int r = 0; r < 4; r++) {
                    int row = m0 + wr * (64 * BMH) + i * 16 + quad * 4 + r;
                    int b = row >> 11, s = row & (SEQ - 1);
                    float pos = (float)posids[row];
                    float sn, cs;
                    __sincosf(pos * fr, &sn, &cs);
#pragma unroll
                    for (int p = 0; p < 2; p++) {
                        float x1 = acc[i][2 * p][r] + bias2[n0k + p * 128 + dl];
                        float x2 = acc[i][2 * p + 1][r] + bias2[n0k + p * 128 + dl + 64];
                        size_t obase = ((size_t)(b * NKV + h0 + p) * SEQ + s) * HD;
                        O[obase + dl]      = f2bf(x1 * cs - x2 * sn);
                        O[obase + dl + 64] = f2bf(x2 * cs + x1 * sn);
                    }
                }
        } else {  // V path: transposed store
            ushort_t* O = (ushort_t*)out3;
            const int n0v = n0 - 2560;
#pragma unroll
            for (int i = 0; i < IM; i++)
#pragma unroll
                for (int r = 0; r < 4; r++) {
                    int row = m0 + wr * (64 * BMH) + i * 16 + quad * 4 + r;
                    int b = row >> 11, s = row & (SEQ - 1);
#pragma unroll
                    for (int j = 0; j < 4; j++) {
                        int ct = wc + 4 * j;                     // 0..15
                        int h = (n0v >> 7) + (ct >> 3);          // kv head
                        int d = (ct & 7) * 16 + l16;             // head dim 0..127
                        float v = acc[i][j][r] + bias3[n0v + ct * 16 + l16];
                        O[((size_t)(b * NKV + h) * HD + d) * SEQ + s] = f2bf(v);
                    }
                }
        }
    }
}

// ---------------- causal GQA flash attention, balanced-pair Q64 subtiles ----------------
// Qr [B][NH][S][HD], Kr [B][NKV][S][HD], Vt [B][NKV][HD][S] -> Attn bf16 [B*S][HIDDEN]
// Block x handles q-tile qa = x (subtile 0) and qb = 31-x (subtile 1), 64 rows each.
// Per-block MFMA-subtile-steps = (qa+1)+(qb+1) = 33 -- UNIFORM across all 512 blocks,
// so both co-resident blocks run full-duration (8 waves/CU sustained, no tail).
// K,V double-buffered in LDS; counted vmcnt(8) keeps next tile's loads in flight.
__global__ __launch_bounds__(256) void flash(const ushort_t* __restrict__ Qr,
                                             const ushort_t* __restrict__ Kr,
                                             const ushort_t* __restrict__ Vt,
                                             ushort_t* __restrict__ Attn) {
    __shared__ __align__(16) ushort_t Ksh[2 * 4 * 64 * 32];   // 32 KB
    __shared__ __align__(16) ushort_t Vsh[2 * 2 * 128 * 32];  // 32 KB
    __shared__ __align__(16) ushort_t Ps[4 * 16 * 72];        // 9 KB, per-wave
    const int tid = threadIdx.x;
    const int w = tid >> 6, lane = tid & 63, quad = lane >> 4, l16 = lane & 15;
    const int x = blockIdx.x, h = blockIdx.y, b = blockIdx.z;
    const int qa = x, qb = 31 - x;      // the block's two q-tiles (64 rows each)
    const int nkt = qb + 1;             // kv-tiles 0..qb (covers qa's 0..qa prefix)
    const int hkv = h >> 2;
    const ushort_t* Kg = Kr + ((size_t)(b * NKV + hkv) * SEQ) * HD;
    const ushort_t* Vg = Vt + ((size_t)(b * NKV + hkv) * HD) * SEQ;

    const int p = lane >> 2;
    const int gc8 = (((lane & 3) ^ ((lane >> 3) & 3)) << 3);
    const ushort_t* kst = Kg + (size_t)p * HD + w * 32 + gc8;
    const ushort_t* vst = Vg + (size_t)((w & 1) * 64 + p) * SEQ + (w >> 1) * 32 + gc8;
    ushort_t* ksl = Ksh + w * 2048;
    ushort_t* vsl = Vsh + (w >> 1) * 4096 + (w & 1) * 2048;

    auto stage = [&](int bi, int kv0) {
        const ushort_t* gk = kst + (size_t)kv0 * HD;
        ushort_t* lk = ksl + bi * 8192;
        load_lds16(gk, lk);
        load_lds16(gk + (size_t)16 * HD, lk + 512);
        load_lds16(gk + (size_t)32 * HD, lk + 1024);
        load_lds16(gk + (size_t)48 * HD, lk + 1536);
        const ushort_t* gv = vst + kv0;
        ushort_t* lv = vsl + bi * 8192;
        load_lds16(gv, lv);
        load_lds16(gv + (size_t)16 * SEQ, lv + 512);
        load_lds16(gv + (size_t)32 * SEQ, lv + 1024);
        load_lds16(gv + (size_t)48 * SEQ, lv + 1536);
    };

    // Q fragments in registers: subtile 0 -> qa, subtile 1 -> qb
    bf16x8 aq[2][4];
#pragma unroll
    for (int st = 0; st < 2; st++) {
        const int qst = st ? qb : qa;
        const size_t qrow = ((size_t)(b * NH + h) * SEQ + qst * 64 + w * 16 + l16) * HD;
#pragma unroll
        for (int kc = 0; kc < 4; kc++)
            aq[st][kc] = *(const bf16x8*)&Qr[qrow + kc * 32 + quad * 8];
    }

    f32x4 o[2][8];
#pragma unroll
    for (int st = 0; st < 2; st++)
#pragma unroll
        for (int j = 0; j < 8; j++)
#pragma unroll
            for (int e = 0; e < 4; e++) o[st][j][e] = 0.0f;
    f32x4 ls2[2];
#pragma unroll
    for (int st = 0; st < 2; st++)
        for (int e = 0; e < 4; e++) ls2[st][e] = 0.0f;
    bf16x8 ones;
#pragma unroll
    for (int e = 0; e < 8; e++) ones[e] = (short)0x3F80;  // bf16 1.0

    ushort_t* Pw = &Ps[w * 16 * 72];
    const int rsw8 = ((l16 >> 1) & 3) << 3;

    stage(0, 0);
    asm volatile("s_waitcnt vmcnt(0)" ::: "memory");
    __builtin_amdgcn_s_barrier();

    for (int kt = 0; kt < nkt; kt++) {
        const int kv0 = kt * 64;
        const int cur = kt & 1;
        if (kt + 1 < nkt) {
            stage(cur ^ 1, kv0 + 64);
            asm volatile("s_waitcnt vmcnt(8)" ::: "memory");
        } else {
            asm volatile("s_waitcnt vmcnt(0)" ::: "memory");
        }
        __builtin_amdgcn_s_barrier();

        const ushort_t* Kb = Ksh + cur * 8192;
        const ushort_t* Vb = Vsh + cur * 8192;

#pragma unroll
        for (int st = 0; st < 2; st++) {
            const int qst = st ? qb : qa;
            if (st == 0 && kt > qa) continue;  // qa's causal range exhausted

            f32x4 sa[4];
#pragma unroll
            for (int nt = 0; nt < 4; nt++)
#pragma unroll
                for (int e = 0; e < 4; e++) sa[nt][e] = 0.0f;
#pragma unroll
            for (int kc = 0; kc < 4; kc++) {
#pragma unroll
                for (int nt = 0; nt < 4; nt++) {
                    bf16x8 bk = *(const bf16x8*)&Kb[kc * 2048 + nt * 512 + l16 * 32 +
                                                    ((quad * 8) ^ rsw8)];
                    sa[nt] = mfma16(aq[st][kc], bk, sa[nt]);
                }
            }

            // causal mask on this subtile's diagonal tile
            if (kt == qst) {
#pragma unroll
                for (int nt = 0; nt < 4; nt++)
#pragma unroll
                    for (int r = 0; r < 4; r++) {
                        int kvg = kv0 + nt * 16 + l16;
                        int qg = qst * 64 + w * 16 + quad * 4 + r;
                        if (kvg > qg) sa[nt][r] = -1e30f;
                    }
            }

#pragma unroll
            for (int nt = 0; nt < 4; nt++)
#pragma unroll
                for (int r = 0; r < 4; r++)
                    Pw[(quad * 4 + r) * 72 + nt * 16 + l16] = f2bf_trunc(__expf(sa[nt][r]));

#pragma unroll
            for (int kc = 0; kc < 2; kc++) {
                bf16x8 ap = *(const bf16x8*)&Pw[l16 * 72 + kc * 32 + quad * 8];
                ls2[st] = mfma16(ap, ones, ls2[st]);
#pragma unroll
                for (int j = 0; j < 8; j++) {
                    bf16x8 bv = *(const bf16x8*)&Vb[kc * 4096 + (j * 16 + l16) * 32 +
                                                    ((quad * 8) ^ rsw8)];
                    o[st][j] = mfma16(ap, bv, o[st][j]);
                }
            }
        }
        asm volatile("s_barrier" ::: "memory");
    }

#pragma unroll
    for (int st = 0; st < 2; st++) {
        const int qst = st ? qb : qa;
#pragma unroll
        for (int r = 0; r < 4; r++) {
            float inv = 1.0f / ls2[st][r];
            int row = b * SEQ + qst * 64 + w * 16 + quad * 4 + r;
            size_t obase = (size_t)row * HIDDEN + h * HD;
#pragma unroll
            for (int j = 0; j < 8; j++) Attn[obase + j * 16 + l16] = f2bf(o[st][j][r] * inv);
        }
    }
}

extern "C" void kernel_launch(void* const* d_in, const int* in_sizes, int n_in,
                              void* d_out, int out_size, void* d_ws, size_t ws_size,
                              hipStream_t stream) {
    const float* hs = (const float*)d_in[0];
    const int* posids = (const int*)d_in[1];
    const float* Wq = (const float*)d_in[2];
    const float* bq = (const float*)d_in[3];
    const float* Wk = (const float*)d_in[4];
    const float* bk = (const float*)d_in[5];
    const float* Wv = (const float*)d_in[6];
    const float* bv = (const float*)d_in[7];
    const float* Wo = (const float*)d_in[8];
    const float* bo = (const float*)d_in[9];
    float* out = (float*)d_out;

    char* ws = (char*)d_ws;
    size_t off = 0;
    auto alloc = [&](size_t bytes) {
        char* p = ws + off;
        off += (bytes + 255) & ~(size_t)255;
        return p;
    };
    ushort_t* Xb     = (ushort_t*)alloc(4096ull * 2048 * 2);
    ushort_t* WqkvT  = (ushort_t*)alloc(3072ull * 2048 * 2);
    ushort_t* WoT    = (ushort_t*)alloc(2048ull * 2048 * 2);
    ushort_t* Qr     = (ushort_t*)alloc((size_t)BATCH * NH * SEQ * HD * 2);
    ushort_t* Kr     = (ushort_t*)alloc((size_t)BATCH * NKV * SEQ * HD * 2);
    ushort_t* Vtr    = (ushort_t*)alloc((size_t)BATCH * NKV * HD * SEQ * 2);
    ushort_t* Attn   = (ushort_t*)alloc(4096ull * 2048 * 2);

    convert_x<<<4096 * 2048 / 4 / 256, 256, 0, stream>>>(hs, Xb, 4096 * 2048 / 4);
    transpose_all<<<dim3(32, 32, 4), 256, 0, stream>>>(Wq, Wk, Wv, Wo, WqkvT, WoT);

    gemm256<2, 2><<<dim3(12, 16), 512, 0, stream>>>(Xb, WqkvT, bq, bk, bv,
                                                    Qr, Kr, Vtr, 4096, 3072, 2048, posids);

    flash<<<dim3(16, NH, BATCH), 256, 0, stream>>>(Qr, Kr, Vtr, Attn);

    gemm256<0, 1><<<dim3(8, 32), 512, 0, stream>>>(Attn, WoT, bo, nullptr, nullptr,
                                                   out, nullptr, nullptr, 4096, 2048, 2048, nullptr);
}

// Round 8
// 298.727 us; speedup vs baseline: 1.4647x; 1.0541x over previous
//
#include <hip/hip_runtime.h>
#include <cmath>

#define HIDDEN 2048
#define NH 16
#define NKV 4
#define HD 128
#define SEQ 2048
#define BATCH 2

typedef unsigned short ushort_t;
typedef short bf16x8 __attribute__((ext_vector_type(8)));
typedef float f32x4 __attribute__((ext_vector_type(4)));
typedef ushort_t u16x4 __attribute__((ext_vector_type(4)));

__device__ __forceinline__ ushort_t f2bf(float f) {
    union { float f; unsigned int u; } v; v.f = f;
    unsigned int r = v.u + 0x7fffu + ((v.u >> 16) & 1u);
    return (ushort_t)(r >> 16);
}
__device__ __forceinline__ ushort_t f2bf_trunc(float f) {
    union { float f; unsigned int u; } v; v.f = f;
    return (ushort_t)(v.u >> 16);
}

__device__ __forceinline__ f32x4 mfma16(bf16x8 a, bf16x8 b, f32x4 c) {
    return __builtin_amdgcn_mfma_f32_16x16x32_bf16(a, b, c, 0, 0, 0);
}

// async global -> LDS, 16B per lane. LDS dst is wave-uniform base + lane*16.
__device__ __forceinline__ void load_lds16(const void* g, void* l) {
    __builtin_amdgcn_global_load_lds((const __attribute__((address_space(1))) unsigned int*)g,
                                     (__attribute__((address_space(3))) unsigned int*)l,
                                     16, 0, 0);
}

// Zero-conflict LDS tile family (r4-verified, SQ_LDS_BANK_CONFLICT==0 measured):
// [rows][32 shorts] (64-B row stride). Chunk c of row p stored at slot c^((p>>1)&3).
// Staging lane l: row p=l>>2, slot l&3, fetches global chunk (l&3)^((l>>3)&3).
// Reader of chunk q at row r uses slot q^((r>>1)&3).

// ---------------- fused prep: weight transpose (z<4) + activation convert (z>=4) ----
// z=0: Wq -> WqkvT rows 0..2047 | z=1: Wk -> rows 2048..2559 | z=2: Wv -> rows 2560..3071
// z=3: Wo -> WoT | z=4..11: hs fp32 -> Xb bf16 (2M float4 slices)
__global__ __launch_bounds__(256) void prep(const float* __restrict__ Wq,
                                            const float* __restrict__ Wk,
                                            const float* __restrict__ Wv,
                                            const float* __restrict__ Wo,
                                            ushort_t* __restrict__ WqkvT,
                                            ushort_t* __restrict__ WoT,
                                            const float* __restrict__ hs,
                                            ushort_t* __restrict__ Xb) {
    const int z = blockIdx.z;
    const int t = threadIdx.x;
    if (z >= 4) {
        // convert: 8 slices x 1024 blocks x 256 threads x 1 float4 = 2M float4
        int g = (((z - 4) * 32 + blockIdx.y) * 32 + blockIdx.x) * 256 + t;
        float4 v = ((const float4*)hs)[g];
        u16x4 o;
        o[0] = f2bf(v.x); o[1] = f2bf(v.y); o[2] = f2bf(v.z); o[3] = f2bf(v.w);
        ((u16x4*)Xb)[g] = o;
        return;
    }
    const float* W;
    ushort_t* WT;
    int N;
    if (z == 0)      { W = Wq; WT = WqkvT;                        N = 2048; }
    else if (z == 1) { W = Wk; WT = WqkvT + 2048ull * 2048;       N = 512;  }
    else if (z == 2) { W = Wv; WT = WqkvT + 2560ull * 2048;       N = 512;  }
    else             { W = Wo; WT = WoT;                          N = 2048; }
    const int K = 2048;
    const int n0 = blockIdx.x * 64, k0 = blockIdx.y * 64;
    if (n0 >= N) return;
    __shared__ ushort_t T[64][72];
    for (int idx = t; idx < 64 * 16; idx += 256) {
        int r = idx >> 4, c4 = (idx & 15) << 2;
        float4 v = *(const float4*)&W[(size_t)(k0 + r) * N + n0 + c4];
        T[r][c4 + 0] = f2bf(v.x); T[r][c4 + 1] = f2bf(v.y);
        T[r][c4 + 2] = f2bf(v.z); T[r][c4 + 3] = f2bf(v.w);
    }
    __syncthreads();
    for (int idx = t; idx < 64 * 16; idx += 256) {
        int n = idx >> 4, kg = (idx & 15) << 2;
        u16x4 o;
        o[0] = T[kg + 0][n]; o[1] = T[kg + 1][n];
        o[2] = T[kg + 2][n]; o[3] = T[kg + 3][n];
        *(u16x4*)&WT[(size_t)(n0 + n) * K + k0 + kg] = o;
    }
}

// ---------------- (BM)x256-tile GEMM, 8-phase counted-vmcnt schedule ----------------
// C = A[M][K] * Bt[N][K]^T + bias, fused epilogues.  BMH = BM/128.
// 512 threads = 8 waves (2 row x 4 col); per-wave output (64*BMH)x64 (acc[4*BMH][4]).
// BK=64 split into 2 kc-planes of [rows][32 shorts] (64-B stride, zero-conflict
// family). Full 2-tile double buffer.  Phases (BMH=2): P1:A0 P2:A1 P3:B0 P4:B1;
// (BMH=1): P1:A P2:B0 P3:B1 P4:-.  vmcnt(2) at P1 & P4; each phase's ds_reads touch
// only data guaranteed landed by the previous phase's wait+barrier; never drain to 0
// mid-loop.  P1/P2 read kc-plane 0, P3/P4 plane 1.
// Column tiles per wave INTERLEAVED {wc, wc+4, wc+8, wc+12} (RoPE pair in-wave).
template <int MODE, int BMH>
__global__ __launch_bounds__(512) void gemm256(const ushort_t* __restrict__ A,
                                               const ushort_t* __restrict__ Bt,
                                               const float* __restrict__ bias,
                                               const float* __restrict__ bias2,
                                               const float* __restrict__ bias3,
                                               void* __restrict__ out,
                                               void* __restrict__ out2,
                                               void* __restrict__ out3,
                                               int M, int N, int K,
                                               const int* __restrict__ posids) {
    constexpr int IM = 4 * BMH;            // acc row-fragments per wave
    constexpr int APL = BMH * 128 * 32;    // A kc-plane size (shorts)
    constexpr int BPL = 256 * 32;          // B kc-plane size (shorts)
    __shared__ __align__(16) ushort_t Asb[2 * 2 * APL];  // [buf][kc][rows][32]
    __shared__ __align__(16) ushort_t Bsb[2 * 2 * BPL];
    const int tid = threadIdx.x;
    const int w = tid >> 6, lane = tid & 63, quad = lane >> 4, l16 = lane & 15;
    const int wr = w >> 2, wc = w & 3;  // 2x4 wave grid
    const int m0 = blockIdx.y * (128 * BMH), n0 = blockIdx.x * 256;

    f32x4 acc[IM][4];
#pragma unroll
    for (int i = 0; i < IM; i++)
#pragma unroll
        for (int j = 0; j < 4; j++)
#pragma unroll
            for (int e = 0; e < 4; e++) acc[i][j][e] = 0.0f;

    // staging: lane -> row l>>2 (16 rows/instr), swizzled chunk (l&3)^((l>>3)&3)
    const int srow = lane >> 2;
    const int gc8 = (((lane & 3) ^ ((lane >> 3) & 3)) << 3);

    auto stageA = [&](int t, int buf, int ha) {
        const ushort_t* g = A + (size_t)(m0 + ha * 128 + w * 16 + srow) * K + t * 64 + gc8;
        ushort_t* l = &Asb[buf * 2 * APL + (ha * 128 + w * 16) * 32];
        load_lds16(g, l);              // kc = 0 plane
        load_lds16(g + 32, l + APL);   // kc = 1 plane
    };
    auto stageB = [&](int t, int buf, int ha) {
        const ushort_t* g = Bt + (size_t)(n0 + ha * 128 + w * 16 + srow) * K + t * 64 + gc8;
        ushort_t* l = &Bsb[buf * 2 * BPL + (ha * 128 + w * 16) * 32];
        load_lds16(g, l);
        load_lds16(g + 32, l + BPL);
    };

    // reader: slot = (quad ^ ((row>>1)&3))*8; row parity spreads banks (64-B stride)
    const int slot = ((quad ^ ((l16 >> 1) & 3)) << 3);
    const int arow = (wr * (64 * BMH) + l16) * 32 + slot;  // + i*512
    const int brow = (wc * 16 + l16) * 32 + slot;          // + j*2048

    const int nt = K >> 6;  // K-tiles of 64

    // prologue
    stageA(0, 0, 0);
    if constexpr (BMH == 2) stageA(0, 0, 1);
    stageB(0, 0, 0);
    stageB(0, 0, 1);
    asm volatile("s_waitcnt vmcnt(2)" ::: "memory");
    __builtin_amdgcn_s_barrier();
    __builtin_amdgcn_sched_barrier(0);

    bf16x8 a[IM];
    for (int u = 0; u < nt; ++u) {
        const int bu = u & 1, bn = bu ^ 1;
        const bool pf = (u + 1 < nt);
        const ushort_t* Ap0 = &Asb[bu * 2 * APL];        // kc=0 plane
        const ushort_t* Ap1 = Ap0 + APL;                 // kc=1 plane
        const ushort_t* Bp0 = &Bsb[bu * 2 * BPL];
        const ushort_t* Bp1 = Bp0 + BPL;

        // ---- P1: kc=0, j={0,1} ----
#pragma unroll
        for (int i = 0; i < IM; i++) a[i] = *(const bf16x8*)&Ap0[arow + i * 512];
        bf16x8 b0 = *(const bf16x8*)&Bp0[brow];
        bf16x8 b1 = *(const bf16x8*)&Bp0[brow + 2048];
        if (pf) { stageA(u + 1, bn, 0); asm volatile("s_waitcnt vmcnt(2)" ::: "memory"); }
        else    { asm volatile("s_waitcnt vmcnt(0)" ::: "memory"); }
        __builtin_amdgcn_s_barrier();
        __builtin_amdgcn_sched_barrier(0);
        __builtin_amdgcn_s_setprio(1);
#pragma unroll
        for (int i = 0; i < IM; i++) {
            acc[i][0] = mfma16(a[i], b0, acc[i][0]);
            acc[i][1] = mfma16(a[i], b1, acc[i][1]);
        }
        __builtin_amdgcn_s_setprio(0);
        __builtin_amdgcn_sched_barrier(0);
        __builtin_amdgcn_s_barrier();
        __builtin_amdgcn_sched_barrier(0);

        // ---- P2: kc=0, j={2,3} ----
        bf16x8 b2 = *(const bf16x8*)&Bp0[brow + 4096];
        bf16x8 b3 = *(const bf16x8*)&Bp0[brow + 6144];
        if (pf) {
            if constexpr (BMH == 2) stageA(u + 1, bn, 1);
            else                    stageB(u + 1, bn, 0);
        }
        __builtin_amdgcn_s_barrier();
        __builtin_amdgcn_sched_barrier(0);
        __builtin_amdgcn_s_setprio(1);
#pragma unroll
        for (int i = 0; i < IM; i++) {
            acc[i][2] = mfma16(a[i], b2, acc[i][2]);
            acc[i][3] = mfma16(a[i], b3, acc[i][3]);
        }
        __builtin_amdgcn_s_setprio(0);
        __builtin_amdgcn_sched_barrier(0);
        __builtin_amdgcn_s_barrier();
        __builtin_amdgcn_sched_barrier(0);

        // ---- P3: kc=1, j={0,1} ----
#pragma unroll
        for (int i = 0; i < IM; i++) a[i] = *(const bf16x8*)&Ap1[arow + i * 512];
        b0 = *(const bf16x8*)&Bp1[brow];
        b1 = *(const bf16x8*)&Bp1[brow + 2048];
        if (pf) {
            if constexpr (BMH == 2) stageB(u + 1, bn, 0);
            else                    stageB(u + 1, bn, 1);
        }
        __builtin_amdgcn_s_barrier();
        __builtin_amdgcn_sched_barrier(0);
        __builtin_amdgcn_s_setprio(1);
#pragma unroll
        for (int i = 0; i < IM; i++) {
            acc[i][0] = mfma16(a[i], b0, acc[i][0]);
            acc[i][1] = mfma16(a[i], b1, acc[i][1]);
        }
        __builtin_amdgcn_s_setprio(0);
        __builtin_amdgcn_sched_barrier(0);
        __builtin_amdgcn_s_barrier();
        __builtin_amdgcn_sched_barrier(0);

        // ---- P4: kc=1, j={2,3} ----
        b2 = *(const bf16x8*)&Bp1[brow + 4096];
        b3 = *(const bf16x8*)&Bp1[brow + 6144];
        if (pf) {
            if constexpr (BMH == 2) stageB(u + 1, bn, 1);
            asm volatile("s_waitcnt vmcnt(2)" ::: "memory");
        }
        __builtin_amdgcn_s_barrier();
        __builtin_amdgcn_sched_barrier(0);
        __builtin_amdgcn_s_setprio(1);
#pragma unroll
        for (int i = 0; i < IM; i++) {
            acc[i][2] = mfma16(a[i], b2, acc[i][2]);
            acc[i][3] = mfma16(a[i], b3, acc[i][3]);
        }
        __builtin_amdgcn_s_setprio(0);
        __builtin_amdgcn_sched_barrier(0);
        __builtin_amdgcn_s_barrier();
        __builtin_amdgcn_sched_barrier(0);
    }

    // ---- epilogues (unchanged, verified) ----
    if (MODE == 0) {
        float* O = (float*)out;
#pragma unroll
        for (int i = 0; i < IM; i++)
#pragma unroll
            for (int r = 0; r < 4; r++) {
                int row = m0 + wr * (64 * BMH) + i * 16 + quad * 4 + r;
#pragma unroll
                for (int j = 0; j < 4; j++) {
                    int col = n0 + (wc + 4 * j) * 16 + l16;
                    O[(size_t)row * N + col] = acc[i][j][r] + bias[col];
                }
            }
    } else {  // MODE 2: fused QKV (BMH == 2)
        if (n0 < 2048) {  // Q path: RoPE + scale; block covers heads h0, h0+1
            ushort_t* O = (ushort_t*)out;
            const int h0 = n0 >> 7;
            const float scale = 0.08838834764831845f;
            const int dl = wc * 16 + l16;  // 0..63, same for both heads
            const float fr = __expf(-0.21586735246819178f * (float)dl);
#pragma unroll
            for (int i = 0; i < IM; i++)
#pragma unroll
                for (int r = 0; r < 4; r++) {
                    int row = m0 + wr * (64 * BMH) + i * 16 + quad * 4 + r;  // b*SEQ + s
                    int b = row >> 11, s = row & (SEQ - 1);
                    float pos = (float)posids[row];
                    float sn, cs;
                    __sincosf(pos * fr, &sn, &cs);
#pragma unroll
                    for (int p = 0; p < 2; p++) {
                        float x1 = acc[i][2 * p][r] + bias[n0 + p * 128 + dl];
                        float x2 = acc[i][2 * p + 1][r] + bias[n0 + p * 128 + dl + 64];
                        size_t obase = ((size_t)(b * NH + h0 + p) * SEQ + s) * HD;
                        O[obase + dl]      = f2bf((x1 * cs - x2 * sn) * scale);
                        O[obase + dl + 64] = f2bf((x2 * cs + x1 * sn) * scale);
                    }
                }
        } else if (n0 < 2560) {  // K path: RoPE; block covers kv-heads h0, h0+1
            ushort_t* O = (ushort_t*)out2;
            const int n0k = n0 - 2048;
            const int h0 = n0k >> 7;
            const int dl = wc * 16 + l16;
            const float fr = __expf(-0.21586735246819178f * (float)dl);
#pragma unroll
            for (int i = 0; i < IM; i++)
#pragma unroll
                for (int r = 0; r < 4; r++) {
                    int row = m0 + wr * (64 * BMH) + i * 16 + quad * 4 + r;
                    int b = row >> 11, s = row & (SEQ - 1);
                    float pos = (float)posids[row];
                    float sn, cs;
                    __sincosf(pos * fr, &sn, &cs);
#pragma unroll
                    for (int p = 0; p < 2; p++) {
                        float x1 = acc[i][2 * p][r] + bias2[n0k + p * 128 + dl];
                        float x2 = acc[i][2 * p + 1][r] + bias2[n0k + p * 128 + dl + 64];
                        size_t obase = ((size_t)(b * NKV + h0 + p) * SEQ + s) * HD;
                        O[obase + dl]      = f2bf(x1 * cs - x2 * sn);
                        O[obase + dl + 64] = f2bf(x2 * cs + x1 * sn);
                    }
                }
        } else {  // V path: transposed store
            ushort_t* O = (ushort_t*)out3;
            const int n0v = n0 - 2560;
#pragma unroll
            for (int i = 0; i < IM; i++)
#pragma unroll
                for (int r = 0; r < 4; r++) {
                    int row = m0 + wr * (64 * BMH) + i * 16 + quad * 4 + r;
                    int b = row >> 11, s = row & (SEQ - 1);
#pragma unroll
                    for (int j = 0; j < 4; j++) {
                        int ct = wc + 4 * j;                     // 0..15
                        int h = (n0v >> 7) + (ct >> 3);          // kv head
                        int d = (ct & 7) * 16 + l16;             // head dim 0..127
                        float v = acc[i][j][r] + bias3[n0v + ct * 16 + l16];
                        O[((size_t)(b * NKV + h) * HD + d) * SEQ + s] = f2bf(v);
                    }
                }
        }
    }
}

// ---------------- causal GQA flash attention, balanced-pair Q64 subtiles ----------------
// (unchanged from round 6 -- passed, <77.6 us)
__global__ __launch_bounds__(256) void flash(const ushort_t* __restrict__ Qr,
                                             const ushort_t* __restrict__ Kr,
                                             const ushort_t* __restrict__ Vt,
                                             ushort_t* __restrict__ Attn) {
    __shared__ __align__(16) ushort_t Ksh[2 * 4 * 64 * 32];   // 32 KB
    __shared__ __align__(16) ushort_t Vsh[2 * 2 * 128 * 32];  // 32 KB
    __shared__ __align__(16) ushort_t Ps[4 * 16 * 72];        // 9 KB, per-wave
    const int tid = threadIdx.x;
    const int w = tid >> 6, lane = tid & 63, quad = lane >> 4, l16 = lane & 15;
    const int x = blockIdx.x, h = blockIdx.y, b = blockIdx.z;
    const int qa = x, qb = 31 - x;      // the block's two q-tiles (64 rows each)
    const int nkt = qb + 1;             // kv-tiles 0..qb (covers qa's 0..qa prefix)
    const int hkv = h >> 2;
    const ushort_t* Kg = Kr + ((size_t)(b * NKV + hkv) * SEQ) * HD;
    const ushort_t* Vg = Vt + ((size_t)(b * NKV + hkv) * HD) * SEQ;

    const int p = lane >> 2;
    const int gc8 = (((lane & 3) ^ ((lane >> 3) & 3)) << 3);
    const ushort_t* kst = Kg + (size_t)p * HD + w * 32 + gc8;
    const ushort_t* vst = Vg + (size_t)((w & 1) * 64 + p) * SEQ + (w >> 1) * 32 + gc8;
    ushort_t* ksl = Ksh + w * 2048;
    ushort_t* vsl = Vsh + (w >> 1) * 4096 + (w & 1) * 2048;

    auto stage = [&](int bi, int kv0) {
        const ushort_t* gk = kst + (size_t)kv0 * HD;
        ushort_t* lk = ksl + bi * 8192;
        load_lds16(gk, lk);
        load_lds16(gk + (size_t)16 * HD, lk + 512);
        load_lds16(gk + (size_t)32 * HD, lk + 1024);
        load_lds16(gk + (size_t)48 * HD, lk + 1536);
        const ushort_t* gv = vst + kv0;
        ushort_t* lv = vsl + bi * 8192;
        load_lds16(gv, lv);
        load_lds16(gv + (size_t)16 * SEQ, lv + 512);
        load_lds16(gv + (size_t)32 * SEQ, lv + 1024);
        load_lds16(gv + (size_t)48 * SEQ, lv + 1536);
    };

    // Q fragments in registers: subtile 0 -> qa, subtile 1 -> qb
    bf16x8 aq[2][4];
#pragma unroll
    for (int st = 0; st < 2; st++) {
        const int qst = st ? qb : qa;
        const size_t qrow = ((size_t)(b * NH + h) * SEQ + qst * 64 + w * 16 + l16) * HD;
#pragma unroll
        for (int kc = 0; kc < 4; kc++)
            aq[st][kc] = *(const bf16x8*)&Qr[qrow + kc * 32 + quad * 8];
    }

    f32x4 o[2][8];
#pragma unroll
    for (int st = 0; st < 2; st++)
#pragma unroll
        for (int j = 0; j < 8; j++)
#pragma unroll
            for (int e = 0; e < 4; e++) o[st][j][e] = 0.0f;
    f32x4 ls2[2];
#pragma unroll
    for (int st = 0; st < 2; st++)
        for (int e = 0; e < 4; e++) ls2[st][e] = 0.0f;
    bf16x8 ones;
#pragma unroll
    for (int e = 0; e < 8; e++) ones[e] = (short)0x3F80;  // bf16 1.0

    ushort_t* Pw = &Ps[w * 16 * 72];
    const int rsw8 = ((l16 >> 1) & 3) << 3;

    stage(0, 0);
    asm volatile("s_waitcnt vmcnt(0)" ::: "memory");
    __builtin_amdgcn_s_barrier();

    for (int kt = 0; kt < nkt; kt++) {
        const int kv0 = kt * 64;
        const int cur = kt & 1;
        if (kt + 1 < nkt) {
            stage(cur ^ 1, kv0 + 64);
            asm volatile("s_waitcnt vmcnt(8)" ::: "memory");
        } else {
            asm volatile("s_waitcnt vmcnt(0)" ::: "memory");
        }
        __builtin_amdgcn_s_barrier();

        const ushort_t* Kb = Ksh + cur * 8192;
        const ushort_t* Vb = Vsh + cur * 8192;

#pragma unroll
        for (int st = 0; st < 2; st++) {
            const int qst = st ? qb : qa;
            if (st == 0 && kt > qa) continue;  // qa's causal range exhausted

            f32x4 sa[4];
#pragma unroll
            for (int nt = 0; nt < 4; nt++)
#pragma unroll
                for (int e = 0; e < 4; e++) sa[nt][e] = 0.0f;
#pragma unroll
            for (int kc = 0; kc < 4; kc++) {
#pragma unroll
                for (int nt = 0; nt < 4; nt++) {
                    bf16x8 bk = *(const bf16x8*)&Kb[kc * 2048 + nt * 512 + l16 * 32 +
                                                    ((quad * 8) ^ rsw8)];
                    sa[nt] = mfma16(aq[st][kc], bk, sa[nt]);
                }
            }

            // causal mask on this subtile's diagonal tile
            if (kt == qst) {
#pragma unroll
                for (int nt = 0; nt < 4; nt++)
#pragma unroll
                    for (int r = 0; r < 4; r++) {
                        int kvg = kv0 + nt * 16 + l16;
                        int qg = qst * 64 + w * 16 + quad * 4 + r;
                        if (kvg > qg) sa[nt][r] = -1e30f;
                    }
            }

#pragma unroll
            for (int nt = 0; nt < 4; nt++)
#pragma unroll
                for (int r = 0; r < 4; r++)
                    Pw[(quad * 4 + r) * 72 + nt * 16 + l16] = f2bf_trunc(__expf(sa[nt][r]));

#pragma unroll
            for (int kc = 0; kc < 2; kc++) {
                bf16x8 ap = *(const bf16x8*)&Pw[l16 * 72 + kc * 32 + quad * 8];
                ls2[st] = mfma16(ap, ones, ls2[st]);
#pragma unroll
                for (int j = 0; j < 8; j++) {
                    bf16x8 bv = *(const bf16x8*)&Vb[kc * 4096 + (j * 16 + l16) * 32 +
                                                    ((quad * 8) ^ rsw8)];
                    o[st][j] = mfma16(ap, bv, o[st][j]);
                }
            }
        }
        asm volatile("s_barrier" ::: "memory");
    }

#pragma unroll
    for (int st = 0; st < 2; st++) {
        const int qst = st ? qb : qa;
#pragma unroll
        for (int r = 0; r < 4; r++) {
            float inv = 1.0f / ls2[st][r];
            int row = b * SEQ + qst * 64 + w * 16 + quad * 4 + r;
            size_t obase = (size_t)row * HIDDEN + h * HD;
#pragma unroll
            for (int j = 0; j < 8; j++) Attn[obase + j * 16 + l16] = f2bf(o[st][j][r] * inv);
        }
    }
}

extern "C" void kernel_launch(void* const* d_in, const int* in_sizes, int n_in,
                              void* d_out, int out_size, void* d_ws, size_t ws_size,
                              hipStream_t stream) {
    const float* hs = (const float*)d_in[0];
    const int* posids = (const int*)d_in[1];
    const float* Wq = (const float*)d_in[2];
    const float* bq = (const float*)d_in[3];
    const float* Wk = (const float*)d_in[4];
    const float* bk = (const float*)d_in[5];
    const float* Wv = (const float*)d_in[6];
    const float* bv = (const float*)d_in[7];
    const float* Wo = (const float*)d_in[8];
    const float* bo = (const float*)d_in[9];
    float* out = (float*)d_out;

    char* ws = (char*)d_ws;
    size_t off = 0;
    auto alloc = [&](size_t bytes) {
        char* p = ws + off;
        off += (bytes + 255) & ~(size_t)255;
        return p;
    };
    ushort_t* Xb     = (ushort_t*)alloc(4096ull * 2048 * 2);
    ushort_t* WqkvT  = (ushort_t*)alloc(3072ull * 2048 * 2);
    ushort_t* WoT    = (ushort_t*)alloc(2048ull * 2048 * 2);
    ushort_t* Qr     = (ushort_t*)alloc((size_t)BATCH * NH * SEQ * HD * 2);
    ushort_t* Kr     = (ushort_t*)alloc((size_t)BATCH * NKV * SEQ * HD * 2);
    ushort_t* Vtr    = (ushort_t*)alloc((size_t)BATCH * NKV * HD * SEQ * 2);
    ushort_t* Attn   = (ushort_t*)alloc(4096ull * 2048 * 2);

    prep<<<dim3(32, 32, 12), 256, 0, stream>>>(Wq, Wk, Wv, Wo, WqkvT, WoT, hs, Xb);

    gemm256<2, 2><<<dim3(12, 16), 512, 0, stream>>>(Xb, WqkvT, bq, bk, bv,
                                                    Qr, Kr, Vtr, 4096, 3072, 2048, posids);

    flash<<<dim3(16, NH, BATCH), 256, 0, stream>>>(Qr, Kr, Vtr, Attn);

    gemm256<0, 1><<<dim3(8, 32), 512, 0, stream>>>(Attn, WoT, bo, nullptr, nullptr,
                                                   out, nullptr, nullptr, 4096, 2048, 2048, nullptr);
}